// Round 6
// baseline (539.127 us; speedup 1.0000x reference)
//
#include <hip/hip_runtime.h>
#include <math.h>

namespace {
constexpr int kNE = 512;          // num codebook entries
constexpr int kED = 64;           // embed dim
constexpr int kHW = 4096;         // 64*64 spatial
constexpr int kNTiles = 2048;     // 64-token tiles
constexpr int kNTok = 131072;
constexpr int kTokPerBlk = 64;
constexpr int kThreads = 256;

// output float offsets (return order: loss, out, perplexity, encodings,
// new_embedding, cluster, new_ema_w)
constexpr size_t O_LOSS    = 0;
constexpr size_t O_OUT     = 1;
constexpr size_t O_PERP    = 8388609;
constexpr size_t O_ENC     = 8388610;   // byte-align 8 (float2 ok, float4 NOT)
constexpr size_t O_NEWEMB  = 75497474;
constexpr size_t O_CLUSTER = 75530242;
constexpr size_t O_NEWEMAW = 75530754;

// workspace float offsets
constexpr size_t F_IDX   = 0;         // 131072 ints
constexpr size_t F_LOSS  = 131072;    // 1 float
constexpr size_t F_SE32  = 131584;    // 512 floats; reused as start[512] ints after argmin
constexpr size_t F_SE64  = 132096;    // 512 doubles
constexpr size_t F_EHI   = 133120;    // 512x64 ushort; reused as parts[64][512] ints after argmin
constexpr size_t F_ELO   = 149504;    // 512x64 ushort (second half of parts region)
constexpr size_t F_CNT   = 165888;    // 512 floats
constexpr size_t F_DW    = 166400;    // 32768 floats
constexpr size_t F_AUX   = 199168;    // flat (token-major x) OR partials
constexpr int    kPartStride = 33280; // 32768 dw + 512 hist (fallback)

constexpr float kMargin = 0.01f;      // computed-gap below which we fp64-rescan

typedef __attribute__((ext_vector_type(8))) short short8;
typedef __attribute__((ext_vector_type(4))) float f32x4;
typedef __attribute__((ext_vector_type(2))) float f32x2;
typedef __attribute__((ext_vector_type(4))) unsigned short us4;
}

__device__ __forceinline__ unsigned short f2bf(float f) {
  unsigned u = __builtin_bit_cast(unsigned, f);
  unsigned r = (u + 0x7FFFu + ((u >> 16) & 1u)) >> 16;
  return (unsigned short)r;
}
__device__ __forceinline__ float bf2f(unsigned short h) {
  unsigned u = (unsigned)h << 16;
  return __builtin_bit_cast(float, u);
}

// ||e||^2 (fp64 + fp32) and bf16 hi/lo split of the codebook.
extern "C" __global__ void vq_se2(const float* __restrict__ emb,
                                  float* __restrict__ se32,
                                  double* __restrict__ se64,
                                  unsigned short* __restrict__ ehi,
                                  unsigned short* __restrict__ elo) {
  int j = blockIdx.x * blockDim.x + threadIdx.x;
  if (j >= kNE) return;
  const float4* e4 = (const float4*)(emb + (size_t)j * kED);
  double s = 0.0;
  for (int i = 0; i < 16; ++i) {
    float4 v = e4[i];
    s += (double)v.x * v.x + (double)v.y * v.y
       + (double)v.z * v.z + (double)v.w * v.w;
    us4 h, l;
    float f[4] = {v.x, v.y, v.z, v.w};
    unsigned short hh[4], ll[4];
    #pragma unroll
    for (int t = 0; t < 4; ++t) {
      hh[t] = f2bf(f[t]);
      ll[t] = f2bf(f[t] - bf2f(hh[t]));
    }
    h.x = hh[0]; h.y = hh[1]; h.z = hh[2]; h.w = hh[3];
    l.x = ll[0]; l.y = ll[1]; l.z = ll[2]; l.w = ll[3];
    *(us4*)&ehi[(size_t)j * kED + i * 4] = h;
    *(us4*)&elo[(size_t)j * kED + i * 4] = l;
  }
  se64[j] = s;
  se32[j] = (float)s;
}

// MFMA argmin, 38.4 KB LDS -> 4 blocks/CU. No fp32 x tile: bf16 hi/lo split
// happens in registers during the transpose staging; fp64 rescue re-reads
// the (rare) flagged token's exact x from global.
extern "C" __global__ __launch_bounds__(kThreads) void vq_argmin(
    const float* __restrict__ x, const float* __restrict__ emb,
    const float* __restrict__ se32, const double* __restrict__ se64,
    const unsigned short* __restrict__ ehi, const unsigned short* __restrict__ elo,
    int* __restrict__ idx_out) {
  __shared__ __attribute__((aligned(16))) unsigned short ahi[kTokPerBlk][72];
  __shared__ __attribute__((aligned(16))) unsigned short alo[kTokPerBlk][72];
  __shared__ __attribute__((aligned(16))) unsigned short bhi[64][72];
  __shared__ __attribute__((aligned(16))) unsigned short blo[64][72];
  __shared__ float se_t[64];
  __shared__ float tok_best[kTokPerBlk];
  __shared__ float tok_sec[kTokPerBlk];
  __shared__ int   tok_idx[kTokPerBlk];
  __shared__ int   flag_list[kTokPerBlk];
  __shared__ int   flag_cnt;
  __shared__ float xbuf[kED];
  // rescue reduction arrays overlay the dead B tile after the main loop
  double* redd = (double*)&bhi[0][0];   // 2048 B < 9216
  int*    redj = (int*)&blo[0][0];      // 1024 B < 9216

  const int tid = threadIdx.x;
  const int token_base = blockIdx.x * kTokPerBlk;
  const int batch = token_base / kHW;
  const int pos0  = token_base % kHW;     // tiles never cross batch

  if (tid == 0) flag_cnt = 0;

  // ---- stage x tile: transpose + bf16 hi/lo split in registers ----
  // thread (p = tid&63, d0 = tid>>6) owns token p, dims d0*16 .. d0*16+15
  const float* xb = x + (size_t)batch * kED * kHW + pos0;
  {
    const int p  = tid & 63;
    const int d0 = tid >> 6;
    float xv[16];
    #pragma unroll
    for (int i = 0; i < 16; ++i)
      xv[i] = xb[(size_t)(d0 * 16 + i) * kHW + p];   // coalesced per i
    unsigned hp[8], lp[8];
    #pragma unroll
    for (int i = 0; i < 8; ++i) {
      unsigned short h0 = f2bf(xv[2*i]),  h1 = f2bf(xv[2*i+1]);
      unsigned short l0 = f2bf(xv[2*i]   - bf2f(h0));
      unsigned short l1 = f2bf(xv[2*i+1] - bf2f(h1));
      hp[i] = (unsigned)h0 | ((unsigned)h1 << 16);
      lp[i] = (unsigned)l0 | ((unsigned)l1 << 16);
    }
    uint4 h04 = {hp[0], hp[1], hp[2], hp[3]};
    uint4 h48 = {hp[4], hp[5], hp[6], hp[7]};
    uint4 l04 = {lp[0], lp[1], lp[2], lp[3]};
    uint4 l48 = {lp[4], lp[5], lp[6], lp[7]};
    *(uint4*)&ahi[p][d0 * 16]     = h04;
    *(uint4*)&ahi[p][d0 * 16 + 8] = h48;
    *(uint4*)&alo[p][d0 * 16]     = l04;
    *(uint4*)&alo[p][d0 * 16 + 8] = l48;
  }
  __syncthreads();

  // ---- per-wave A fragments (persist across all chunks) ----
  const int lane = tid & 63;
  const int wv   = tid >> 6;
  const int qd   = lane >> 4;
  const int ml   = lane & 15;
  const int arow = wv * 16 + ml;
  const char* abase_h = (const char*)&ahi[0][0] + arow * 144 + qd * 16;
  const char* abase_l = (const char*)&alo[0][0] + arow * 144 + qd * 16;
  short8 a_h0 = *(const short8*)(abase_h);
  short8 a_h1 = *(const short8*)(abase_h + 64);
  short8 a_l0 = *(const short8*)(abase_l);
  short8 a_l1 = *(const short8*)(abase_l + 64);

  float bestv[4], secv[4];
  int   bestj[4];
  #pragma unroll
  for (int r = 0; r < 4; ++r) { bestv[r] = INFINITY; secv[r] = INFINITY; bestj[r] = 0; }

  // ---- 8 chunks of 64 codes: bf16x3 MFMA distances ----
  for (int c0 = 0; c0 < kNE; c0 += 64) {
    __syncthreads();
    {
      const char* srch = (const char*)ehi + (size_t)c0 * 128;
      const char* srcl = (const char*)elo + (size_t)c0 * 128;
      #pragma unroll
      for (int i = 0; i < 2; ++i) {
        int q = i * kThreads + tid;     // 0..511 (64 rows x 8 segs)
        int row = q >> 3, seg = q & 7;
        *(float4*)((char*)&bhi[0][0] + row * 144 + seg * 16) =
            *(const float4*)(srch + row * 128 + seg * 16);
        *(float4*)((char*)&blo[0][0] + row * 144 + seg * 16) =
            *(const float4*)(srcl + row * 128 + seg * 16);
      }
      if (tid < 64) se_t[tid] = se32[c0 + tid];
    }
    __syncthreads();

    for (int nt = 0; nt < 4; nt += 2) {
      const int cc0 = nt * 16 + ml;
      const int cc1 = cc0 + 16;
      const char* b0h = (const char*)&bhi[0][0] + cc0 * 144 + qd * 16;
      const char* b0l = (const char*)&blo[0][0] + cc0 * 144 + qd * 16;
      const char* b1h = (const char*)&bhi[0][0] + cc1 * 144 + qd * 16;
      const char* b1l = (const char*)&blo[0][0] + cc1 * 144 + qd * 16;
      short8 bh00 = *(const short8*)(b0h);
      short8 bh01 = *(const short8*)(b0h + 64);
      short8 bl00 = *(const short8*)(b0l);
      short8 bl01 = *(const short8*)(b0l + 64);
      short8 bh10 = *(const short8*)(b1h);
      short8 bh11 = *(const short8*)(b1h + 64);
      short8 bl10 = *(const short8*)(b1l);
      short8 bl11 = *(const short8*)(b1l + 64);

      f32x4 acc0 = {0.f, 0.f, 0.f, 0.f};
      f32x4 acc1 = {0.f, 0.f, 0.f, 0.f};
      acc0 = __builtin_amdgcn_mfma_f32_16x16x32_bf16(a_h0, bh00, acc0, 0, 0, 0);
      acc1 = __builtin_amdgcn_mfma_f32_16x16x32_bf16(a_h0, bh10, acc1, 0, 0, 0);
      acc0 = __builtin_amdgcn_mfma_f32_16x16x32_bf16(a_h1, bh01, acc0, 0, 0, 0);
      acc1 = __builtin_amdgcn_mfma_f32_16x16x32_bf16(a_h1, bh11, acc1, 0, 0, 0);
      acc0 = __builtin_amdgcn_mfma_f32_16x16x32_bf16(a_l0, bh00, acc0, 0, 0, 0);
      acc1 = __builtin_amdgcn_mfma_f32_16x16x32_bf16(a_l0, bh10, acc1, 0, 0, 0);
      acc0 = __builtin_amdgcn_mfma_f32_16x16x32_bf16(a_l1, bh01, acc0, 0, 0, 0);
      acc1 = __builtin_amdgcn_mfma_f32_16x16x32_bf16(a_l1, bh11, acc1, 0, 0, 0);
      acc0 = __builtin_amdgcn_mfma_f32_16x16x32_bf16(a_h0, bl00, acc0, 0, 0, 0);
      acc1 = __builtin_amdgcn_mfma_f32_16x16x32_bf16(a_h0, bl10, acc1, 0, 0, 0);
      acc0 = __builtin_amdgcn_mfma_f32_16x16x32_bf16(a_h1, bl01, acc0, 0, 0, 0);
      acc1 = __builtin_amdgcn_mfma_f32_16x16x32_bf16(a_h1, bl11, acc1, 0, 0, 0);

      const int j0 = c0 + cc0;
      const int j1 = c0 + cc1;
      const float s0 = se_t[cc0];
      const float s1 = se_t[cc1];
      #pragma unroll
      for (int r = 0; r < 4; ++r) {
        float v0 = s0 - 2.f * acc0[r];
        if (v0 < bestv[r]) { secv[r] = bestv[r]; bestv[r] = v0; bestj[r] = j0; }
        else secv[r] = fminf(secv[r], v0);
        float v1 = s1 - 2.f * acc1[r];
        if (v1 < bestv[r]) { secv[r] = bestv[r]; bestv[r] = v1; bestj[r] = j1; }
        else secv[r] = fminf(secv[r], v1);
      }
    }
  }

  // ---- cross-lane merge within each 16-lane quad group ----
  #pragma unroll
  for (int off = 1; off < 16; off <<= 1) {
    #pragma unroll
    for (int r = 0; r < 4; ++r) {
      float ov = __shfl_xor(bestv[r], off, 16);
      float os = __shfl_xor(secv[r], off, 16);
      int   oj = __shfl_xor(bestj[r], off, 16);
      bool take = (ov < bestv[r]) || (ov == bestv[r] && oj < bestj[r]);
      float loser = take ? bestv[r] : ov;
      bestv[r] = take ? ov : bestv[r];
      bestj[r] = take ? oj : bestj[r];
      secv[r]  = fminf(fminf(loser, os), secv[r]);
    }
  }
  if (ml == 0) {
    #pragma unroll
    for (int r = 0; r < 4; ++r) {
      int m = wv * 16 + qd * 4 + r;
      tok_best[m] = bestv[r];
      tok_sec[m]  = secv[r];
      tok_idx[m]  = bestj[r];
    }
  }
  __syncthreads();

  if (tid < kTokPerBlk) {
    if (tok_sec[tid] - tok_best[tid] < kMargin) {
      int p = atomicAdd(&flag_cnt, 1);
      flag_list[p] = tid;
    }
  }
  __syncthreads();

  // ---- exact fp64 rescan for flagged tokens (rare) ----
  const int nflag = flag_cnt;
  for (int fi = 0; fi < nflag; ++fi) {
    const int tr = flag_list[fi];
    if (tid < kED) xbuf[tid] = xb[(size_t)tid * kHW + tr];  // exact fp32 x
    __syncthreads();
    double db = 1e300; int dbj = 0;
    #pragma unroll 1
    for (int jj = 0; jj < 2; ++jj) {
      int j = tid * 2 + jj;
      const float* er = emb + (size_t)j * kED;
      double a0 = 0.0, a1 = 0.0, a2 = 0.0, a3 = 0.0;
      #pragma unroll
      for (int d = 0; d < kED; d += 4) {
        a0 = __builtin_fma((double)xbuf[d+0], (double)er[d+0], a0);
        a1 = __builtin_fma((double)xbuf[d+1], (double)er[d+1], a1);
        a2 = __builtin_fma((double)xbuf[d+2], (double)er[d+2], a2);
        a3 = __builtin_fma((double)xbuf[d+3], (double)er[d+3], a3);
      }
      double dist = se64[j] - 2.0 * ((a0 + a1) + (a2 + a3));
      if (dist < db || (dist == db && j < dbj)) { db = dist; dbj = j; }
    }
    redd[tid] = db; redj[tid] = dbj;
    __syncthreads();
    for (int s2 = kThreads / 2; s2 > 0; s2 >>= 1) {
      if (tid < s2) {
        double v = redd[tid + s2]; int j = redj[tid + s2];
        if (v < redd[tid] || (v == redd[tid] && j < redj[tid])) {
          redd[tid] = v; redj[tid] = j;
        }
      }
      __syncthreads();
    }
    if (tid == 0) tok_idx[tr] = redj[0];
    __syncthreads();
  }

  if (tid < kTokPerBlk) idx_out[token_base + tid] = tok_idx[tid];
}

// ---- counting sort for dw: hist -> scan -> scatter -> chunked seg-sum ----
extern "C" __global__ __launch_bounds__(kThreads) void vq_hist(
    const int* __restrict__ idx, int* __restrict__ parts) {
  __shared__ int h[kNE];
  const int tid = threadIdx.x, b = blockIdx.x;
  h[tid] = 0; h[tid + 256] = 0;
  __syncthreads();
  #pragma unroll
  for (int it = 0; it < 8; ++it)
    atomicAdd(&h[idx[b * 2048 + it * 256 + tid]], 1);
  __syncthreads();
  parts[b * kNE + tid] = h[tid];
  parts[b * kNE + tid + 256] = h[tid + 256];
}

extern "C" __global__ __launch_bounds__(512) void vq_scan(
    int* __restrict__ parts, int* __restrict__ start,
    float* __restrict__ cnt) {
  __shared__ int pl[64 * kNE];   // 128 KB
  __shared__ int sh[kNE];
  const int c = threadIdx.x;     // 0..511
  for (int i = c; i < 64 * kNE; i += 512) pl[i] = parts[i];
  __syncthreads();
  int run = 0;
  #pragma unroll 1
  for (int p = 0; p < 64; ++p) {
    int t = pl[p * kNE + c];
    pl[p * kNE + c] = run;
    run += t;
  }
  sh[c] = run;
  cnt[c] = (float)run;
  __syncthreads();
  #pragma unroll 1
  for (int off = 1; off < kNE; off <<= 1) {
    int t = (c >= off) ? sh[c - off] : 0;
    __syncthreads();
    sh[c] += t;
    __syncthreads();
  }
  int st = sh[c] - run;
  start[c] = st;
  #pragma unroll 1
  for (int p = 0; p < 64; ++p)
    parts[p * kNE + c] = st + pl[p * kNE + c];
}

// Writes PACKED entries: (code << 17) | token   (code<512, token<2^17)
extern "C" __global__ __launch_bounds__(kThreads) void vq_scatter(
    const int* __restrict__ idx, const int* __restrict__ parts,
    int* __restrict__ sorted) {
  __shared__ int cur[kNE];
  const int tid = threadIdx.x, b = blockIdx.x;
  cur[tid] = parts[b * kNE + tid];
  cur[tid + 256] = parts[b * kNE + tid + 256];
  __syncthreads();
  #pragma unroll
  for (int it = 0; it < 8; ++it) {
    int i = b * 2048 + it * 256 + tid;
    int c = idx[i];
    int pos = atomicAdd(&cur[c], 1);
    sorted[pos] = (c << 17) | i;
  }
}

// Load-balanced dw: 1024 blocks x 128 sorted tokens, register run-accumulation
// over the non-decreasing code sequence, atomic flush on code change.
extern "C" __global__ __launch_bounds__(kThreads) void vq_dw_chunk(
    const float* __restrict__ flat, const int* __restrict__ sorted,
    float* __restrict__ dwf) {
  __shared__ int spk[128];
  const int tid = threadIdx.x;
  const int base = blockIdx.x * 128;
  if (tid < 128) spk[tid] = sorted[base + tid];
  __syncthreads();
  const int tt = tid >> 6, d = tid & 63;
  int cur_c = -1;
  float acc = 0.f;
  #pragma unroll 1
  for (int bi = 0; bi < 8; ++bi) {
    int p = tt * 32 + bi * 4;
    int k0 = spk[p], k1 = spk[p + 1], k2 = spk[p + 2], k3 = spk[p + 3];
    float v0 = flat[(size_t)(k0 & 131071) * kED + d];
    float v1 = flat[(size_t)(k1 & 131071) * kED + d];
    float v2 = flat[(size_t)(k2 & 131071) * kED + d];
    float v3 = flat[(size_t)(k3 & 131071) * kED + d];
    int c0 = k0 >> 17, c1 = k1 >> 17, c2 = k2 >> 17, c3 = k3 >> 17;
    if (c0 != cur_c) {
      if (cur_c >= 0) atomicAdd(&dwf[cur_c * kED + d], acc);
      acc = 0.f; cur_c = c0;
    }
    acc += v0;
    if (c1 != cur_c) { atomicAdd(&dwf[cur_c * kED + d], acc); acc = 0.f; cur_c = c1; }
    acc += v1;
    if (c2 != cur_c) { atomicAdd(&dwf[cur_c * kED + d], acc); acc = 0.f; cur_c = c2; }
    acc += v2;
    if (c3 != cur_c) { atomicAdd(&dwf[cur_c * kED + d], acc); acc = 0.f; cur_c = c3; }
    acc += v3;
  }
  atomicAdd(&dwf[cur_c * kED + d], acc);
}

// ---- streaming outputs ----
extern "C" __global__ __launch_bounds__(kThreads) void vq_enc(
    const int* __restrict__ idx, float* __restrict__ enc) {
  __shared__ int ti[kTokPerBlk];
  const int tid = threadIdx.x;
  const int token_base = blockIdx.x * kTokPerBlk;
  if (tid < kTokPerBlk) ti[tid] = idx[token_base + tid];
  __syncthreads();
  f32x2* encb2 = (f32x2*)(enc + (size_t)token_base * kNE);
  #pragma unroll 4
  for (int i = 0; i < 64; ++i) {
    int q = i * kThreads + tid;   // float2 idx, 0..16383
    int row = q >> 8;
    int c2  = (q & 255) * 2;
    int bi = ti[row];
    f32x2 v;
    v.x = (bi == c2)     ? 1.f : 0.f;
    v.y = (bi == c2 + 1) ? 1.f : 0.f;
    __builtin_nontemporal_store(v, &encb2[q]);
  }
}

// out (straight-through, NCHW) + commitment loss + token-major flat for dw.
extern "C" __global__ __launch_bounds__(kThreads) void vq_out(
    const float* __restrict__ x, const float* __restrict__ emb,
    const int* __restrict__ idx, float* __restrict__ out_q,
    float* __restrict__ loss_sum, float* __restrict__ flat_ws,
    int write_flat) {
  __shared__ float xt[kTokPerBlk][65];
  __shared__ float qt[kTokPerBlk * 65];
  __shared__ int ti[kTokPerBlk];
  __shared__ float lred[4];
  const int tid = threadIdx.x;
  const int token_base = blockIdx.x * kTokPerBlk;
  const int batch = token_base / kHW;
  const int pos0  = token_base % kHW;
  if (tid < kTokPerBlk) ti[tid] = idx[token_base + tid];
  // stage x tile (transpose NCHW -> token-major)
  const float* xb = x + (size_t)batch * kED * kHW + pos0;
  {
    const int p  = tid & 63;
    const int d0 = tid >> 6;
    #pragma unroll
    for (int i = 0; i < 16; ++i) {
      int d = i * 4 + d0;
      xt[p][d] = xb[(size_t)d * kHW + p];
    }
  }
  __syncthreads();
  {
    int rr = tid >> 2;
    int c0 = (tid & 3) * 16;
    const float* er = emb + (size_t)ti[rr] * kED;
    #pragma unroll
    for (int i = 0; i < 4; ++i) {
      float4 v = *(const float4*)(er + c0 + i * 4);
      qt[rr * 65 + c0 + i * 4 + 0] = v.x;
      qt[rr * 65 + c0 + i * 4 + 1] = v.y;
      qt[rr * 65 + c0 + i * 4 + 2] = v.z;
      qt[rr * 65 + c0 + i * 4 + 3] = v.w;
    }
  }
  __syncthreads();
  float lacc = 0.f;
  {
    float* outb = out_q + (size_t)batch * kED * kHW + pos0;
    const int p  = tid & 63;
    const int c0 = tid >> 6;
    #pragma unroll
    for (int i = 0; i < 16; ++i) {
      int c = i * 4 + c0;
      float inv  = xt[p][c];
      float qv   = qt[p * 65 + c];
      float diff = qv - inv;
      __builtin_nontemporal_store(inv + diff, &outb[(size_t)c * kHW + p]);
      lacc = __builtin_fmaf(diff, diff, lacc);
    }
  }
  if (write_flat) {
    const int r  = tid >> 2;
    const int d0 = (tid & 3) * 16;
    float* dst = flat_ws + (size_t)(token_base + r) * kED + d0;
    #pragma unroll
    for (int i = 0; i < 4; ++i) {
      f32x4 v = {xt[r][d0 + i*4], xt[r][d0 + i*4 + 1],
                 xt[r][d0 + i*4 + 2], xt[r][d0 + i*4 + 3]};
      *(f32x4*)(dst + i * 4) = v;
    }
  }
  #pragma unroll
  for (int off = 32; off > 0; off >>= 1) lacc += __shfl_down(lacc, off, 64);
  if ((tid & 63) == 0) lred[tid >> 6] = lacc;
  __syncthreads();
  if (tid == 0)
    atomicAdd(loss_sum, (lred[0] + lred[1]) + (lred[2] + lred[3]));
}

// ---- fallback path (small ws): per-block LDS partials + dense reduce ----
extern "C" __global__ __launch_bounds__(kThreads) void vq_dw_part(
    const float* __restrict__ x, const int* __restrict__ idx,
    float* __restrict__ part, int G) {
  __shared__ float dwacc[kNE * kED];
  __shared__ int   hist[kNE];
  __shared__ float flat[kTokPerBlk][65];
  __shared__ int   idxs[kTokPerBlk];
  const int tid = threadIdx.x;
  #pragma unroll
  for (int i = 0; i < kNE * kED / kThreads; ++i) dwacc[i * kThreads + tid] = 0.f;
  for (int i = tid; i < kNE; i += kThreads) hist[i] = 0;
  __syncthreads();
  for (int tile = blockIdx.x; tile < kNTiles; tile += G) {
    const int token_base = tile * kTokPerBlk;
    const int batch = token_base / kHW;
    const int pos0  = token_base % kHW;
    const float* xb = x + (size_t)batch * kED * kHW + pos0;
    {
      const int p  = tid & 63;
      const int d0 = tid >> 6;
      #pragma unroll
      for (int i = 0; i < 16; ++i) {
        int d = i * 4 + d0;
        flat[p][d] = xb[(size_t)d * kHW + p];
      }
    }
    if (tid < kTokPerBlk) idxs[tid] = idx[token_base + tid];
    __syncthreads();
    {
      const int w = tid >> 6;
      const int d = tid & 63;
      #pragma unroll
      for (int i = 0; i < 16; ++i) {
        int rr = w + i * 4;
        atomicAdd(&dwacc[idxs[rr] * kED + d], flat[rr][d]);
      }
    }
    if (tid < kTokPerBlk) atomicAdd(&hist[idxs[tid]], 1);
    __syncthreads();
  }
  float* dst = part + (size_t)blockIdx.x * kPartStride;
  #pragma unroll
  for (int i = 0; i < kNE * kED / kThreads / 4; ++i) {
    int q = i * kThreads + tid;
    *(float4*)&dst[q * 4] = *(float4*)&dwacc[q * 4];
  }
  #pragma unroll
  for (int i = 0; i < kNE / kThreads; ++i) {
    int q = i * kThreads + tid;
    dst[kNE * kED + q] = (float)hist[q];
  }
}

extern "C" __global__ void vq_red(const float* __restrict__ part,
                                  float* __restrict__ dwf,
                                  float* __restrict__ cnt, int G) {
  int i = blockIdx.x * blockDim.x + threadIdx.x;
  if (i >= kPartStride) return;
  float s0 = 0.f, s1 = 0.f, s2 = 0.f, s3 = 0.f;
  int p = 0;
  for (; p + 3 < G; p += 4) {
    s0 += part[(size_t)(p + 0) * kPartStride + i];
    s1 += part[(size_t)(p + 1) * kPartStride + i];
    s2 += part[(size_t)(p + 2) * kPartStride + i];
    s3 += part[(size_t)(p + 3) * kPartStride + i];
  }
  for (; p < G; ++p) s0 += part[(size_t)p * kPartStride + i];
  float s = (s0 + s1) + (s2 + s3);
  if (i < kNE * kED) dwf[i] = s;
  else cnt[i - kNE * kED] = s;
}

extern "C" __global__ __launch_bounds__(kThreads) void vq_dw_atomic(
    const float* __restrict__ x, const int* __restrict__ idx,
    float* __restrict__ dwf, float* __restrict__ cnt) {
  __shared__ float flat[kTokPerBlk][65];
  __shared__ int   idxs[kTokPerBlk];
  const int tid = threadIdx.x;
  const int token_base = blockIdx.x * kTokPerBlk;
  const int batch = token_base / kHW;
  const int pos0  = token_base % kHW;
  const float* xb = x + (size_t)batch * kED * kHW + pos0;
  {
    const int p  = tid & 63;
    const int d0 = tid >> 6;
    #pragma unroll
    for (int i = 0; i < 16; ++i) {
      int d = i * 4 + d0;
      flat[p][d] = xb[(size_t)d * kHW + p];
    }
  }
  if (tid < kTokPerBlk) idxs[tid] = idx[token_base + tid];
  __syncthreads();
  {
    int rr = tid >> 2;
    int c0 = (tid & 3) * 16;
    float* dwr = dwf + (size_t)idxs[rr] * kED;
    #pragma unroll
    for (int i = 0; i < 16; ++i) atomicAdd(&dwr[c0 + i], flat[rr][c0 + i]);
  }
  if (tid < kTokPerBlk) atomicAdd(&cnt[idxs[tid]], 1.0f);
}

// cluster Laplace smoothing, perplexity, loss
extern "C" __global__ void vq_fin_a(const float* __restrict__ ema_cs,
                                    const float* __restrict__ counts,
                                    const float* __restrict__ loss_sum,
                                    float* __restrict__ out) {
  __shared__ float red[kNE];
  const int j = threadIdx.x;
  float craw = ema_cs[j] * 0.99f + 0.01f * counts[j];
  red[j] = craw;
  __syncthreads();
  for (int s = kNE / 2; s > 0; s >>= 1) {
    if (j < s) red[j] += red[j + s];
    __syncthreads();
  }
  float k = red[0];
  __syncthreads();
  float clu = (craw + 1e-5f) / (k + kNE * 1e-5f) * k;
  out[O_CLUSTER + j] = clu;
  float avg = counts[j] * (1.0f / 131072.0f);
  float term = avg * logf(avg + 1e-10f);
  red[j] = term;
  __syncthreads();
  for (int s = kNE / 2; s > 0; s >>= 1) {
    if (j < s) red[j] += red[j + s];
    __syncthreads();
  }
  if (j == 0) {
    out[O_PERP] = expf(-red[0]);
    out[O_LOSS] = 0.25f * loss_sum[0] * (1.0f / 8388608.0f);
  }
}

extern "C" __global__ void vq_fin_b(const float* __restrict__ ema_w,
                                    const float* __restrict__ dw,
                                    const float* __restrict__ out_cluster,
                                    float* __restrict__ out) {
  int i = blockIdx.x * blockDim.x + threadIdx.x;   // 0..32767
  int j = i >> 6;
  float nw = ema_w[i] * 0.99f + 0.01f * dw[i];
  out[O_NEWEMAW + i] = nw;
  out[O_NEWEMB + i] = nw / out_cluster[j];
}

extern "C" void kernel_launch(void* const* d_in, const int* in_sizes, int n_in,
                              void* d_out, int out_size, void* d_ws, size_t ws_size,
                              hipStream_t stream) {
  const float* x      = (const float*)d_in[0];
  const float* emb    = (const float*)d_in[1];
  const float* ema_w  = (const float*)d_in[2];
  const float* ema_cs = (const float*)d_in[3];
  float* out = (float*)d_out;
  float* ws  = (float*)d_ws;

  int*    idxb     = (int*)d_ws;
  float*  loss_sum = ws + F_LOSS;
  float*  se32     = ws + F_SE32;
  double* se64     = (double*)(ws + F_SE64);
  unsigned short* ehi = (unsigned short*)(ws + F_EHI);
  unsigned short* elo = (unsigned short*)(ws + F_ELO);
  float*  cnt      = ws + F_CNT;
  float*  dwf      = ws + F_DW;
  float*  aux      = ws + F_AUX;          // flat (token-major x) OR partials
  int*    parts    = (int*)(ws + F_EHI);  // reuse ehi+elo after argmin
  int*    startp   = (int*)(ws + F_SE32); // reuse se32 after argmin
  int*    sorted   = (int*)(out + O_ENC); // enc region scratch; vq_enc runs last

  const size_t need_flat = (F_AUX + (size_t)kNTok * kED) * 4;
  const bool flat_ok = ws_size >= need_flat;
  int G = 0;
  if (!flat_ok) {
    long avail = (long)(ws_size / 4) - (long)F_AUX;
    G = avail > 0 ? (int)(avail / kPartStride) : 0;
    if (G > 256) G = 256;
  }
  const bool part_ok = (G >= 8);

  hipMemsetAsync(ws + F_LOSS, 0, sizeof(float), stream);
  if (flat_ok) {
    hipMemsetAsync(ws + F_DW, 0, kNE * kED * sizeof(float), stream);
  } else if (!part_ok) {
    hipMemsetAsync(ws + F_CNT, 0, (kNE + kNE * kED) * sizeof(float), stream);
  }

  hipLaunchKernelGGL(vq_se2, dim3(2), dim3(256), 0, stream,
                     emb, se32, se64, ehi, elo);
  hipLaunchKernelGGL(vq_argmin, dim3(kNTiles), dim3(kThreads), 0, stream,
                     x, emb, se32, se64, ehi, elo, idxb);
  // out + loss + token-major flat (consumed by dw stage)
  hipLaunchKernelGGL(vq_out, dim3(kNTiles), dim3(kThreads), 0, stream,
                     x, emb, idxb, out + O_OUT, loss_sum, aux, flat_ok ? 1 : 0);
  if (flat_ok) {
    hipLaunchKernelGGL(vq_hist, dim3(64), dim3(kThreads), 0, stream,
                       idxb, parts);
    hipLaunchKernelGGL(vq_scan, dim3(1), dim3(512), 0, stream,
                       parts, startp, cnt);
    hipLaunchKernelGGL(vq_scatter, dim3(64), dim3(kThreads), 0, stream,
                       idxb, parts, sorted);
    hipLaunchKernelGGL(vq_dw_chunk, dim3(kNTok / 128), dim3(kThreads), 0, stream,
                       aux, sorted, dwf);
  } else if (part_ok) {
    hipLaunchKernelGGL(vq_dw_part, dim3(G), dim3(kThreads), 0, stream,
                       x, idxb, aux, G);
    hipLaunchKernelGGL(vq_red, dim3((kPartStride + 255) / 256), dim3(256), 0,
                       stream, aux, dwf, cnt, G);
  } else {
    hipLaunchKernelGGL(vq_dw_atomic, dim3(kNTiles), dim3(kThreads), 0, stream,
                       x, idxb, dwf, cnt);
  }
  // enc last: it overwrites the `sorted` scratch region
  hipLaunchKernelGGL(vq_enc, dim3(kNTiles), dim3(kThreads), 0, stream,
                     idxb, out + O_ENC);
  hipLaunchKernelGGL(vq_fin_a, dim3(1), dim3(kNE), 0, stream,
                     ema_cs, cnt, loss_sum, out);
  hipLaunchKernelGGL(vq_fin_b, dim3(kNE * kED / 256), dim3(256), 0, stream,
                     ema_w, dwf, out + O_CLUSTER, out);
}

// Round 7
// 474.337 us; speedup vs baseline: 1.1366x; 1.1366x over previous
//
#include <hip/hip_runtime.h>
#include <math.h>

namespace {
constexpr int kNE = 512;          // num codebook entries
constexpr int kED = 64;           // embed dim
constexpr int kHW = 4096;         // 64*64 spatial
constexpr int kNTiles = 2048;     // 64-token tiles
constexpr int kNTok = 131072;
constexpr int kTokPerBlk = 64;
constexpr int kThreads = 256;

// output float offsets (return order: loss, out, perplexity, encodings,
// new_embedding, cluster, new_ema_w)
constexpr size_t O_LOSS    = 0;
constexpr size_t O_OUT     = 1;
constexpr size_t O_PERP    = 8388609;
constexpr size_t O_ENC     = 8388610;   // byte-align 8 (float2 ok, float4 NOT)
constexpr size_t O_NEWEMB  = 75497474;
constexpr size_t O_CLUSTER = 75530242;
constexpr size_t O_NEWEMAW = 75530754;

// workspace float offsets
constexpr size_t F_IDX   = 0;         // 131072 ints
constexpr size_t F_LOSS  = 131072;    // 1 float
constexpr size_t F_SE32  = 131584;    // 512 floats; reused as start[512] ints
constexpr size_t F_SE64  = 132096;    // 512 doubles
constexpr size_t F_EHI   = 133120;    // 512x64 ushort; reused as parts[64][512]
constexpr size_t F_ELO   = 149504;    // 512x64 ushort (2nd half of parts)
constexpr size_t F_CNT   = 165888;    // 512 floats
constexpr size_t F_DW    = 166400;    // 32768 floats
constexpr size_t F_AUX   = 199168;    // flat (token-major x) OR partials
constexpr int    kPartStride = 33280; // fallback partials stride

constexpr float kMargin = 0.01f;      // computed-gap below which we fp64-rescan

typedef __attribute__((ext_vector_type(8))) short short8;
typedef __attribute__((ext_vector_type(4))) float f32x4;
typedef __attribute__((ext_vector_type(2))) float f32x2;
typedef __attribute__((ext_vector_type(4))) unsigned short us4;
}

__device__ __forceinline__ unsigned short f2bf(float f) {
  unsigned u = __builtin_bit_cast(unsigned, f);
  unsigned r = (u + 0x7FFFu + ((u >> 16) & 1u)) >> 16;
  return (unsigned short)r;
}
__device__ __forceinline__ float bf2f(unsigned short h) {
  unsigned u = (unsigned)h << 16;
  return __builtin_bit_cast(float, u);
}

// ||e||^2 (fp64 + fp32), bf16 hi/lo codebook split; also zeroes loss_sum.
extern "C" __global__ void vq_se2(const float* __restrict__ emb,
                                  float* __restrict__ se32,
                                  double* __restrict__ se64,
                                  unsigned short* __restrict__ ehi,
                                  unsigned short* __restrict__ elo,
                                  float* __restrict__ loss_sum) {
  int j = blockIdx.x * blockDim.x + threadIdx.x;
  if (j == 0) loss_sum[0] = 0.f;
  if (j >= kNE) return;
  const float4* e4 = (const float4*)(emb + (size_t)j * kED);
  double s = 0.0;
  for (int i = 0; i < 16; ++i) {
    float4 v = e4[i];
    s += (double)v.x * v.x + (double)v.y * v.y
       + (double)v.z * v.z + (double)v.w * v.w;
    us4 h, l;
    float f[4] = {v.x, v.y, v.z, v.w};
    unsigned short hh[4], ll[4];
    #pragma unroll
    for (int t = 0; t < 4; ++t) {
      hh[t] = f2bf(f[t]);
      ll[t] = f2bf(f[t] - bf2f(hh[t]));
    }
    h.x = hh[0]; h.y = hh[1]; h.z = hh[2]; h.w = hh[3];
    l.x = ll[0]; l.y = ll[1]; l.z = ll[2]; l.w = ll[3];
    *(us4*)&ehi[(size_t)j * kED + i * 4] = h;
    *(us4*)&elo[(size_t)j * kED + i * 4] = l;
  }
  se64[j] = s;
  se32[j] = (float)s;
}

// Fused: MFMA argmin + straight-through out + commitment loss + token-major
// flat write. ~38.7 KB LDS. x is read ONCE; inv is reconstructed as hi+lo
// (error ~1e-5 |x|, harmless vs 2% thresholds).
extern "C" __global__ __launch_bounds__(kThreads) void vq_main(
    const float* __restrict__ x, const float* __restrict__ emb,
    const float* __restrict__ se32, const double* __restrict__ se64,
    const unsigned short* __restrict__ ehi, const unsigned short* __restrict__ elo,
    int* __restrict__ idx_out, float* __restrict__ out_q,
    float* __restrict__ loss_sum, float* __restrict__ flat_ws, int write_flat) {
  __shared__ __attribute__((aligned(16))) unsigned short ahi[kTokPerBlk][72];
  __shared__ __attribute__((aligned(16))) unsigned short alo[kTokPerBlk][72];
  __shared__ __attribute__((aligned(16))) char bbuf[64 * 72 * 2 * 2]; // B hi+lo
  __shared__ float se_t[64];
  __shared__ float tok_best[kTokPerBlk];
  __shared__ float tok_sec[kTokPerBlk];
  __shared__ int   tok_idx[kTokPerBlk];
  __shared__ int   flag_list[kTokPerBlk];
  __shared__ int   flag_cnt;
  __shared__ float xbuf[kED];
  __shared__ float lred[4];
  unsigned short* bhi = (unsigned short*)bbuf;            // [64][72]
  unsigned short* blo = (unsigned short*)(bbuf + 9216);   // [64][72]
  // overlays on bbuf after the distance loop:
  double* redd = (double*)bbuf;            // 2048 B (rescue)
  int*    redj = (int*)(bbuf + 2048);      // 1024 B (rescue)
  float*  qt   = (float*)bbuf;             // [64][65] = 16640 B (out phase)

  const int tid = threadIdx.x;
  const int token_base = blockIdx.x * kTokPerBlk;
  const int batch = token_base / kHW;
  const int pos0  = token_base % kHW;     // tiles never cross batch

  if (tid == 0) flag_cnt = 0;

  // ---- stage x tile: transpose + bf16 hi/lo split in registers ----
  const float* xb = x + (size_t)batch * kED * kHW + pos0;
  {
    const int p  = tid & 63;
    const int d0 = tid >> 6;
    float xv[16];
    #pragma unroll
    for (int i = 0; i < 16; ++i)
      xv[i] = xb[(size_t)(d0 * 16 + i) * kHW + p];   // coalesced per i
    unsigned hp[8], lp[8];
    #pragma unroll
    for (int i = 0; i < 8; ++i) {
      unsigned short h0 = f2bf(xv[2*i]),  h1 = f2bf(xv[2*i+1]);
      unsigned short l0 = f2bf(xv[2*i]   - bf2f(h0));
      unsigned short l1 = f2bf(xv[2*i+1] - bf2f(h1));
      hp[i] = (unsigned)h0 | ((unsigned)h1 << 16);
      lp[i] = (unsigned)l0 | ((unsigned)l1 << 16);
    }
    uint4 h04 = {hp[0], hp[1], hp[2], hp[3]};
    uint4 h48 = {hp[4], hp[5], hp[6], hp[7]};
    uint4 l04 = {lp[0], lp[1], lp[2], lp[3]};
    uint4 l48 = {lp[4], lp[5], lp[6], lp[7]};
    *(uint4*)&ahi[p][d0 * 16]     = h04;
    *(uint4*)&ahi[p][d0 * 16 + 8] = h48;
    *(uint4*)&alo[p][d0 * 16]     = l04;
    *(uint4*)&alo[p][d0 * 16 + 8] = l48;
  }
  __syncthreads();

  // ---- per-wave A fragments (persist across all chunks) ----
  const int lane = tid & 63;
  const int wv   = tid >> 6;
  const int qd   = lane >> 4;
  const int ml   = lane & 15;
  const int arow = wv * 16 + ml;
  const char* abase_h = (const char*)&ahi[0][0] + arow * 144 + qd * 16;
  const char* abase_l = (const char*)&alo[0][0] + arow * 144 + qd * 16;
  short8 a_h0 = *(const short8*)(abase_h);
  short8 a_h1 = *(const short8*)(abase_h + 64);
  short8 a_l0 = *(const short8*)(abase_l);
  short8 a_l1 = *(const short8*)(abase_l + 64);

  float bestv[4], secv[4];
  int   bestj[4];
  #pragma unroll
  for (int r = 0; r < 4; ++r) { bestv[r] = INFINITY; secv[r] = INFINITY; bestj[r] = 0; }

  // ---- 8 chunks of 64 codes: bf16x3 MFMA distances ----
  for (int c0 = 0; c0 < kNE; c0 += 64) {
    __syncthreads();
    {
      const char* srch = (const char*)ehi + (size_t)c0 * 128;
      const char* srcl = (const char*)elo + (size_t)c0 * 128;
      #pragma unroll
      for (int i = 0; i < 2; ++i) {
        int q = i * kThreads + tid;     // 0..511 (64 rows x 8 segs)
        int row = q >> 3, seg = q & 7;
        *(float4*)((char*)bhi + row * 144 + seg * 16) =
            *(const float4*)(srch + row * 128 + seg * 16);
        *(float4*)((char*)blo + row * 144 + seg * 16) =
            *(const float4*)(srcl + row * 128 + seg * 16);
      }
      if (tid < 64) se_t[tid] = se32[c0 + tid];
    }
    __syncthreads();

    for (int nt = 0; nt < 4; nt += 2) {
      const int cc0 = nt * 16 + ml;
      const int cc1 = cc0 + 16;
      const char* b0h = (const char*)bhi + cc0 * 144 + qd * 16;
      const char* b0l = (const char*)blo + cc0 * 144 + qd * 16;
      const char* b1h = (const char*)bhi + cc1 * 144 + qd * 16;
      const char* b1l = (const char*)blo + cc1 * 144 + qd * 16;
      short8 bh00 = *(const short8*)(b0h);
      short8 bh01 = *(const short8*)(b0h + 64);
      short8 bl00 = *(const short8*)(b0l);
      short8 bl01 = *(const short8*)(b0l + 64);
      short8 bh10 = *(const short8*)(b1h);
      short8 bh11 = *(const short8*)(b1h + 64);
      short8 bl10 = *(const short8*)(b1l);
      short8 bl11 = *(const short8*)(b1l + 64);

      f32x4 acc0 = {0.f, 0.f, 0.f, 0.f};
      f32x4 acc1 = {0.f, 0.f, 0.f, 0.f};
      acc0 = __builtin_amdgcn_mfma_f32_16x16x32_bf16(a_h0, bh00, acc0, 0, 0, 0);
      acc1 = __builtin_amdgcn_mfma_f32_16x16x32_bf16(a_h0, bh10, acc1, 0, 0, 0);
      acc0 = __builtin_amdgcn_mfma_f32_16x16x32_bf16(a_h1, bh01, acc0, 0, 0, 0);
      acc1 = __builtin_amdgcn_mfma_f32_16x16x32_bf16(a_h1, bh11, acc1, 0, 0, 0);
      acc0 = __builtin_amdgcn_mfma_f32_16x16x32_bf16(a_l0, bh00, acc0, 0, 0, 0);
      acc1 = __builtin_amdgcn_mfma_f32_16x16x32_bf16(a_l0, bh10, acc1, 0, 0, 0);
      acc0 = __builtin_amdgcn_mfma_f32_16x16x32_bf16(a_l1, bh01, acc0, 0, 0, 0);
      acc1 = __builtin_amdgcn_mfma_f32_16x16x32_bf16(a_l1, bh11, acc1, 0, 0, 0);
      acc0 = __builtin_amdgcn_mfma_f32_16x16x32_bf16(a_h0, bl00, acc0, 0, 0, 0);
      acc1 = __builtin_amdgcn_mfma_f32_16x16x32_bf16(a_h0, bl10, acc1, 0, 0, 0);
      acc0 = __builtin_amdgcn_mfma_f32_16x16x32_bf16(a_h1, bl01, acc0, 0, 0, 0);
      acc1 = __builtin_amdgcn_mfma_f32_16x16x32_bf16(a_h1, bl11, acc1, 0, 0, 0);

      const int j0 = c0 + cc0;
      const int j1 = c0 + cc1;
      const float s0 = se_t[cc0];
      const float s1 = se_t[cc1];
      #pragma unroll
      for (int r = 0; r < 4; ++r) {
        float v0 = s0 - 2.f * acc0[r];
        if (v0 < bestv[r]) { secv[r] = bestv[r]; bestv[r] = v0; bestj[r] = j0; }
        else secv[r] = fminf(secv[r], v0);
        float v1 = s1 - 2.f * acc1[r];
        if (v1 < bestv[r]) { secv[r] = bestv[r]; bestv[r] = v1; bestj[r] = j1; }
        else secv[r] = fminf(secv[r], v1);
      }
    }
  }

  // ---- cross-lane merge within each 16-lane quad group ----
  #pragma unroll
  for (int off = 1; off < 16; off <<= 1) {
    #pragma unroll
    for (int r = 0; r < 4; ++r) {
      float ov = __shfl_xor(bestv[r], off, 16);
      float os = __shfl_xor(secv[r], off, 16);
      int   oj = __shfl_xor(bestj[r], off, 16);
      bool take = (ov < bestv[r]) || (ov == bestv[r] && oj < bestj[r]);
      float loser = take ? bestv[r] : ov;
      bestv[r] = take ? ov : bestv[r];
      bestj[r] = take ? oj : bestj[r];
      secv[r]  = fminf(fminf(loser, os), secv[r]);
    }
  }
  if (ml == 0) {
    #pragma unroll
    for (int r = 0; r < 4; ++r) {
      int m = wv * 16 + qd * 4 + r;
      tok_best[m] = bestv[r];
      tok_sec[m]  = secv[r];
      tok_idx[m]  = bestj[r];
    }
  }
  __syncthreads();

  if (tid < kTokPerBlk) {
    if (tok_sec[tid] - tok_best[tid] < kMargin) {
      int p = atomicAdd(&flag_cnt, 1);
      flag_list[p] = tid;
    }
  }
  __syncthreads();   // also: all B reads done -> bbuf reusable

  // ---- exact fp64 rescan for flagged tokens (rare; overlays bbuf) ----
  const int nflag = flag_cnt;
  for (int fi = 0; fi < nflag; ++fi) {
    const int tr = flag_list[fi];
    if (tid < kED) xbuf[tid] = xb[(size_t)tid * kHW + tr];  // exact fp32 x
    __syncthreads();
    double db = 1e300; int dbj = 0;
    #pragma unroll 1
    for (int jj = 0; jj < 2; ++jj) {
      int j = tid * 2 + jj;
      const float* er = emb + (size_t)j * kED;
      double a0 = 0.0, a1 = 0.0, a2 = 0.0, a3 = 0.0;
      #pragma unroll
      for (int d = 0; d < kED; d += 4) {
        a0 = __builtin_fma((double)xbuf[d+0], (double)er[d+0], a0);
        a1 = __builtin_fma((double)xbuf[d+1], (double)er[d+1], a1);
        a2 = __builtin_fma((double)xbuf[d+2], (double)er[d+2], a2);
        a3 = __builtin_fma((double)xbuf[d+3], (double)er[d+3], a3);
      }
      double dist = se64[j] - 2.0 * ((a0 + a1) + (a2 + a3));
      if (dist < db || (dist == db && j < dbj)) { db = dist; dbj = j; }
    }
    redd[tid] = db; redj[tid] = dbj;
    __syncthreads();
    for (int s2 = kThreads / 2; s2 > 0; s2 >>= 1) {
      if (tid < s2) {
        double v = redd[tid + s2]; int j = redj[tid + s2];
        if (v < redd[tid] || (v == redd[tid] && j < redj[tid])) {
          redd[tid] = v; redj[tid] = j;
        }
      }
      __syncthreads();
    }
    if (tid == 0) tok_idx[tr] = redj[0];
    __syncthreads();
  }

  if (tid < kTokPerBlk) idx_out[token_base + tid] = tok_idx[tid];
  __syncthreads();   // rescue overlays done before qt staging

  // ---- gather assigned code rows (fp32) into qt (overlay bbuf) ----
  {
    int rr = tid >> 2;
    int c0 = (tid & 3) * 16;
    const float* er = emb + (size_t)tok_idx[rr] * kED;
    #pragma unroll
    for (int i = 0; i < 4; ++i) {
      float4 v = *(const float4*)(er + c0 + i * 4);
      qt[rr * 65 + c0 + i * 4 + 0] = v.x;
      qt[rr * 65 + c0 + i * 4 + 1] = v.y;
      qt[rr * 65 + c0 + i * 4 + 2] = v.z;
      qt[rr * 65 + c0 + i * 4 + 3] = v.w;
    }
  }
  __syncthreads();

  // ---- out (straight-through, NCHW, NT) + loss; inv = hi+lo reconstruction ----
  float lacc = 0.f;
  {
    float* outb = out_q + (size_t)batch * kED * kHW + pos0;
    const int p  = tid & 63;
    const int c0 = tid >> 6;
    #pragma unroll
    for (int i = 0; i < 16; ++i) {
      int c = i * 4 + c0;
      float inv  = bf2f(ahi[p][c]) + bf2f(alo[p][c]);
      float qv   = qt[p * 65 + c];
      float diff = qv - inv;
      __builtin_nontemporal_store(inv + diff, &outb[(size_t)c * kHW + p]);
      lacc = __builtin_fmaf(diff, diff, lacc);
    }
  }

  // ---- token-major flat x for the dw stage (hi+lo reconstruction) ----
  if (write_flat) {
    const int r  = tid >> 2;
    const int d0 = (tid & 3) * 16;
    float* dst = flat_ws + (size_t)(token_base + r) * kED + d0;
    #pragma unroll
    for (int i = 0; i < 4; ++i) {
      f32x4 v;
      #pragma unroll
      for (int t = 0; t < 4; ++t)
        v[t] = bf2f(ahi[r][d0 + i*4 + t]) + bf2f(alo[r][d0 + i*4 + t]);
      *(f32x4*)(dst + i * 4) = v;
    }
  }

  #pragma unroll
  for (int off = 32; off > 0; off >>= 1) lacc += __shfl_down(lacc, off, 64);
  if ((tid & 63) == 0) lred[tid >> 6] = lacc;
  __syncthreads();
  if (tid == 0)
    atomicAdd(loss_sum, (lred[0] + lred[1]) + (lred[2] + lred[3]));
}

// ---- counting sort for dw: hist -> scan -> scatter -> chunked seg-sum ----
// hist also zeroes dwf (64 blocks x 512 floats), saving a memset dispatch.
extern "C" __global__ __launch_bounds__(kThreads) void vq_hist(
    const int* __restrict__ idx, int* __restrict__ parts,
    float* __restrict__ dwf) {
  __shared__ int h[kNE];
  const int tid = threadIdx.x, b = blockIdx.x;
  h[tid] = 0; h[tid + 256] = 0;
  dwf[b * 512 + tid] = 0.f;
  dwf[b * 512 + tid + 256] = 0.f;
  __syncthreads();
  #pragma unroll
  for (int it = 0; it < 8; ++it)
    atomicAdd(&h[idx[b * 2048 + it * 256 + tid]], 1);
  __syncthreads();
  parts[b * kNE + tid] = h[tid];
  parts[b * kNE + tid + 256] = h[tid + 256];
}

extern "C" __global__ __launch_bounds__(512) void vq_scan(
    int* __restrict__ parts, int* __restrict__ start,
    float* __restrict__ cnt) {
  __shared__ int pl[64 * kNE];   // 128 KB
  __shared__ int sh[kNE];
  const int c = threadIdx.x;     // 0..511
  for (int i = c; i < 64 * kNE; i += 512) pl[i] = parts[i];
  __syncthreads();
  int run = 0;
  #pragma unroll 1
  for (int p = 0; p < 64; ++p) {
    int t = pl[p * kNE + c];
    pl[p * kNE + c] = run;
    run += t;
  }
  sh[c] = run;
  cnt[c] = (float)run;
  __syncthreads();
  #pragma unroll 1
  for (int off = 1; off < kNE; off <<= 1) {
    int t = (c >= off) ? sh[c - off] : 0;
    __syncthreads();
    sh[c] += t;
    __syncthreads();
  }
  int st = sh[c] - run;
  start[c] = st;
  #pragma unroll 1
  for (int p = 0; p < 64; ++p)
    parts[p * kNE + c] = st + pl[p * kNE + c];
}

// Writes PACKED entries: (code << 17) | token   (code<512, token<2^17)
extern "C" __global__ __launch_bounds__(kThreads) void vq_scatter(
    const int* __restrict__ idx, const int* __restrict__ parts,
    int* __restrict__ sorted) {
  __shared__ int cur[kNE];
  const int tid = threadIdx.x, b = blockIdx.x;
  cur[tid] = parts[b * kNE + tid];
  cur[tid + 256] = parts[b * kNE + tid + 256];
  __syncthreads();
  #pragma unroll
  for (int it = 0; it < 8; ++it) {
    int i = b * 2048 + it * 256 + tid;
    int c = idx[i];
    int pos = atomicAdd(&cur[c], 1);
    sorted[pos] = (c << 17) | i;
  }
}

// Load-balanced dw: 1024 blocks x 128 sorted tokens, register run-accumulation
// over the non-decreasing code sequence, atomic flush on code change.
extern "C" __global__ __launch_bounds__(kThreads) void vq_dw_chunk(
    const float* __restrict__ flat, const int* __restrict__ sorted,
    float* __restrict__ dwf) {
  __shared__ int spk[128];
  const int tid = threadIdx.x;
  const int base = blockIdx.x * 128;
  if (tid < 128) spk[tid] = sorted[base + tid];
  __syncthreads();
  const int tt = tid >> 6, d = tid & 63;
  int cur_c = -1;
  float acc = 0.f;
  #pragma unroll 1
  for (int bi = 0; bi < 8; ++bi) {
    int p = tt * 32 + bi * 4;
    int k0 = spk[p], k1 = spk[p + 1], k2 = spk[p + 2], k3 = spk[p + 3];
    float v0 = flat[(size_t)(k0 & 131071) * kED + d];
    float v1 = flat[(size_t)(k1 & 131071) * kED + d];
    float v2 = flat[(size_t)(k2 & 131071) * kED + d];
    float v3 = flat[(size_t)(k3 & 131071) * kED + d];
    int c0 = k0 >> 17, c1 = k1 >> 17, c2 = k2 >> 17, c3 = k3 >> 17;
    if (c0 != cur_c) {
      if (cur_c >= 0) atomicAdd(&dwf[cur_c * kED + d], acc);
      acc = 0.f; cur_c = c0;
    }
    acc += v0;
    if (c1 != cur_c) { atomicAdd(&dwf[cur_c * kED + d], acc); acc = 0.f; cur_c = c1; }
    acc += v1;
    if (c2 != cur_c) { atomicAdd(&dwf[cur_c * kED + d], acc); acc = 0.f; cur_c = c2; }
    acc += v2;
    if (c3 != cur_c) { atomicAdd(&dwf[cur_c * kED + d], acc); acc = 0.f; cur_c = c3; }
    acc += v3;
  }
  atomicAdd(&dwf[cur_c * kED + d], acc);
}

// ---- encodings one-hot stream (runs LAST: overwrites `sorted` scratch) ----
extern "C" __global__ __launch_bounds__(kThreads) void vq_enc(
    const int* __restrict__ idx, float* __restrict__ enc) {
  __shared__ int ti[kTokPerBlk];
  const int tid = threadIdx.x;
  const int token_base = blockIdx.x * kTokPerBlk;
  if (tid < kTokPerBlk) ti[tid] = idx[token_base + tid];
  __syncthreads();
  f32x2* encb2 = (f32x2*)(enc + (size_t)token_base * kNE);
  #pragma unroll 4
  for (int i = 0; i < 64; ++i) {
    int q = i * kThreads + tid;   // float2 idx, 0..16383
    int row = q >> 8;
    int c2  = (q & 255) * 2;
    int bi = ti[row];
    f32x2 v;
    v.x = (bi == c2)     ? 1.f : 0.f;
    v.y = (bi == c2 + 1) ? 1.f : 0.f;
    __builtin_nontemporal_store(v, &encb2[q]);
  }
}

// ---- fallback path (small ws): per-block LDS partials + dense reduce ----
extern "C" __global__ __launch_bounds__(kThreads) void vq_dw_part(
    const float* __restrict__ x, const int* __restrict__ idx,
    float* __restrict__ part, int G) {
  __shared__ float dwacc[kNE * kED];
  __shared__ int   hist[kNE];
  __shared__ float flat[kTokPerBlk][65];
  __shared__ int   idxs[kTokPerBlk];
  const int tid = threadIdx.x;
  #pragma unroll
  for (int i = 0; i < kNE * kED / kThreads; ++i) dwacc[i * kThreads + tid] = 0.f;
  for (int i = tid; i < kNE; i += kThreads) hist[i] = 0;
  __syncthreads();
  for (int tile = blockIdx.x; tile < kNTiles; tile += G) {
    const int token_base = tile * kTokPerBlk;
    const int batch = token_base / kHW;
    const int pos0  = token_base % kHW;
    const float* xb = x + (size_t)batch * kED * kHW + pos0;
    {
      const int p  = tid & 63;
      const int d0 = tid >> 6;
      #pragma unroll
      for (int i = 0; i < 16; ++i) {
        int d = i * 4 + d0;
        flat[p][d] = xb[(size_t)d * kHW + p];
      }
    }
    if (tid < kTokPerBlk) idxs[tid] = idx[token_base + tid];
    __syncthreads();
    {
      const int w = tid >> 6;
      const int d = tid & 63;
      #pragma unroll
      for (int i = 0; i < 16; ++i) {
        int rr = w + i * 4;
        atomicAdd(&dwacc[idxs[rr] * kED + d], flat[rr][d]);
      }
    }
    if (tid < kTokPerBlk) atomicAdd(&hist[idxs[tid]], 1);
    __syncthreads();
  }
  float* dst = part + (size_t)blockIdx.x * kPartStride;
  #pragma unroll
  for (int i = 0; i < kNE * kED / kThreads / 4; ++i) {
    int q = i * kThreads + tid;
    *(float4*)&dst[q * 4] = *(float4*)&dwacc[q * 4];
  }
  #pragma unroll
  for (int i = 0; i < kNE / kThreads; ++i) {
    int q = i * kThreads + tid;
    dst[kNE * kED + q] = (float)hist[q];
  }
}

extern "C" __global__ void vq_red(const float* __restrict__ part,
                                  float* __restrict__ dwf,
                                  float* __restrict__ cnt, int G) {
  int i = blockIdx.x * blockDim.x + threadIdx.x;
  if (i >= kPartStride) return;
  float s0 = 0.f, s1 = 0.f, s2 = 0.f, s3 = 0.f;
  int p = 0;
  for (; p + 3 < G; p += 4) {
    s0 += part[(size_t)(p + 0) * kPartStride + i];
    s1 += part[(size_t)(p + 1) * kPartStride + i];
    s2 += part[(size_t)(p + 2) * kPartStride + i];
    s3 += part[(size_t)(p + 3) * kPartStride + i];
  }
  for (; p < G; ++p) s0 += part[(size_t)p * kPartStride + i];
  float s = (s0 + s1) + (s2 + s3);
  if (i < kNE * kED) dwf[i] = s;
  else cnt[i - kNE * kED] = s;
}

extern "C" __global__ __launch_bounds__(kThreads) void vq_dw_atomic(
    const float* __restrict__ x, const int* __restrict__ idx,
    float* __restrict__ dwf, float* __restrict__ cnt) {
  __shared__ float flat[kTokPerBlk][65];
  __shared__ int   idxs[kTokPerBlk];
  const int tid = threadIdx.x;
  const int token_base = blockIdx.x * kTokPerBlk;
  const int batch = token_base / kHW;
  const int pos0  = token_base % kHW;
  const float* xb = x + (size_t)batch * kED * kHW + pos0;
  {
    const int p  = tid & 63;
    const int d0 = tid >> 6;
    #pragma unroll
    for (int i = 0; i < 16; ++i) {
      int d = i * 4 + d0;
      flat[p][d] = xb[(size_t)d * kHW + p];
    }
  }
  if (tid < kTokPerBlk) idxs[tid] = idx[token_base + tid];
  __syncthreads();
  {
    int rr = tid >> 2;
    int c0 = (tid & 3) * 16;
    float* dwr = dwf + (size_t)idxs[rr] * kED;
    #pragma unroll
    for (int i = 0; i < 16; ++i) atomicAdd(&dwr[c0 + i], flat[rr][c0 + i]);
  }
  if (tid < kTokPerBlk) atomicAdd(&cnt[idxs[tid]], 1.0f);
}

// cluster Laplace smoothing, perplexity, loss
extern "C" __global__ void vq_fin_a(const float* __restrict__ ema_cs,
                                    const float* __restrict__ counts,
                                    const float* __restrict__ loss_sum,
                                    float* __restrict__ out) {
  __shared__ float red[kNE];
  const int j = threadIdx.x;
  float craw = ema_cs[j] * 0.99f + 0.01f * counts[j];
  red[j] = craw;
  __syncthreads();
  for (int s = kNE / 2; s > 0; s >>= 1) {
    if (j < s) red[j] += red[j + s];
    __syncthreads();
  }
  float k = red[0];
  __syncthreads();
  float clu = (craw + 1e-5f) / (k + kNE * 1e-5f) * k;
  out[O_CLUSTER + j] = clu;
  float avg = counts[j] * (1.0f / 131072.0f);
  float term = avg * logf(avg + 1e-10f);
  red[j] = term;
  __syncthreads();
  for (int s = kNE / 2; s > 0; s >>= 1) {
    if (j < s) red[j] += red[j + s];
    __syncthreads();
  }
  if (j == 0) {
    out[O_PERP] = expf(-red[0]);
    out[O_LOSS] = 0.25f * loss_sum[0] * (1.0f / 8388608.0f);
  }
}

extern "C" __global__ void vq_fin_b(const float* __restrict__ ema_w,
                                    const float* __restrict__ dw,
                                    const float* __restrict__ out_cluster,
                                    float* __restrict__ out) {
  int i = blockIdx.x * blockDim.x + threadIdx.x;   // 0..32767
  int j = i >> 6;
  float nw = ema_w[i] * 0.99f + 0.01f * dw[i];
  out[O_NEWEMAW + i] = nw;
  out[O_NEWEMB + i] = nw / out_cluster[j];
}

extern "C" void kernel_launch(void* const* d_in, const int* in_sizes, int n_in,
                              void* d_out, int out_size, void* d_ws, size_t ws_size,
                              hipStream_t stream) {
  const float* x      = (const float*)d_in[0];
  const float* emb    = (const float*)d_in[1];
  const float* ema_w  = (const float*)d_in[2];
  const float* ema_cs = (const float*)d_in[3];
  float* out = (float*)d_out;
  float* ws  = (float*)d_ws;

  int*    idxb     = (int*)d_ws;
  float*  loss_sum = ws + F_LOSS;
  float*  se32     = ws + F_SE32;
  double* se64     = (double*)(ws + F_SE64);
  unsigned short* ehi = (unsigned short*)(ws + F_EHI);
  unsigned short* elo = (unsigned short*)(ws + F_ELO);
  float*  cnt      = ws + F_CNT;
  float*  dwf      = ws + F_DW;
  float*  aux      = ws + F_AUX;          // flat (token-major x) OR partials
  int*    parts    = (int*)(ws + F_EHI);  // reuse ehi+elo after vq_main
  int*    startp   = (int*)(ws + F_SE32); // reuse se32 after vq_main
  int*    sorted   = (int*)(out + O_ENC); // enc region scratch; vq_enc runs last

  const size_t need_flat = (F_AUX + (size_t)kNTok * kED) * 4;
  const bool flat_ok = ws_size >= need_flat;
  int G = 0;
  if (!flat_ok) {
    long avail = (long)(ws_size / 4) - (long)F_AUX;
    G = avail > 0 ? (int)(avail / kPartStride) : 0;
    if (G > 256) G = 256;
  }
  const bool part_ok = (G >= 8);

  if (!flat_ok && !part_ok)
    hipMemsetAsync(ws + F_CNT, 0, (kNE + kNE * kED) * sizeof(float), stream);

  hipLaunchKernelGGL(vq_se2, dim3(2), dim3(256), 0, stream,
                     emb, se32, se64, ehi, elo, loss_sum);
  hipLaunchKernelGGL(vq_main, dim3(kNTiles), dim3(kThreads), 0, stream,
                     x, emb, se32, se64, ehi, elo, idxb, out + O_OUT,
                     loss_sum, aux, flat_ok ? 1 : 0);
  if (flat_ok) {
    hipLaunchKernelGGL(vq_hist, dim3(64), dim3(kThreads), 0, stream,
                       idxb, parts, dwf);
    hipLaunchKernelGGL(vq_scan, dim3(1), dim3(512), 0, stream,
                       parts, startp, cnt);
    hipLaunchKernelGGL(vq_scatter, dim3(64), dim3(kThreads), 0, stream,
                       idxb, parts, sorted);
    hipLaunchKernelGGL(vq_dw_chunk, dim3(kNTok / 128), dim3(kThreads), 0, stream,
                       aux, sorted, dwf);
  } else if (part_ok) {
    hipLaunchKernelGGL(vq_dw_part, dim3(G), dim3(kThreads), 0, stream,
                       x, idxb, aux, G);
    hipLaunchKernelGGL(vq_red, dim3((kPartStride + 255) / 256), dim3(256), 0,
                       stream, aux, dwf, cnt, G);
  } else {
    hipLaunchKernelGGL(vq_dw_atomic, dim3(kNTiles), dim3(kThreads), 0, stream,
                       x, idxb, dwf, cnt);
  }
  // enc last: it overwrites the `sorted` scratch region
  hipLaunchKernelGGL(vq_enc, dim3(kNTiles), dim3(kThreads), 0, stream,
                     idxb, out + O_ENC);
  hipLaunchKernelGGL(vq_fin_a, dim3(1), dim3(kNE), 0, stream,
                     ema_cs, cnt, loss_sum, out);
  hipLaunchKernelGGL(vq_fin_b, dim3(kNE * kED / 256), dim3(256), 0, stream,
                     ema_w, dwf, out + O_CLUSTER, out);
}

// Round 8
// 436.658 us; speedup vs baseline: 1.2347x; 1.0863x over previous
//
#include <hip/hip_runtime.h>
#include <math.h>

namespace {
constexpr int kNE = 512;          // num codebook entries
constexpr int kED = 64;           // embed dim
constexpr int kHW = 4096;         // 64*64 spatial
constexpr int kNTiles = 2048;     // 64-token tiles
constexpr int kNTok = 131072;
constexpr int kTokPerBlk = 64;
constexpr int kThreads = 256;

// output float offsets (return order: loss, out, perplexity, encodings,
// new_embedding, cluster, new_ema_w)
constexpr size_t O_LOSS    = 0;
constexpr size_t O_OUT     = 1;
constexpr size_t O_PERP    = 8388609;
constexpr size_t O_ENC     = 8388610;   // byte-align 8 (float2 ok, float4 NOT)
constexpr size_t O_NEWEMB  = 75497474;
constexpr size_t O_CLUSTER = 75530242;
constexpr size_t O_NEWEMAW = 75530754;

// workspace float offsets
constexpr size_t F_IDX   = 0;         // 131072 ints
constexpr size_t F_LOSS  = 131072;    // 1 float
constexpr size_t F_SE32  = 131584;    // 512 floats; reused as cur[512] ints after main
constexpr size_t F_SE64  = 132096;    // 512 doubles
constexpr size_t F_EHI   = 133120;    // 512x64 ushort
constexpr size_t F_ELO   = 149504;    // 512x64 ushort
constexpr size_t F_CNT   = 165888;    // 512: ghist (int) -> cnt (float) in place
constexpr size_t F_DW    = 166400;    // 32768 floats
constexpr size_t F_AUX   = 199168;    // flat (token-major x) OR partials
constexpr int    kPartStride = 33280; // fallback partials stride

constexpr float kMargin = 0.01f;      // computed-gap below which we fp64-rescan

typedef __attribute__((ext_vector_type(8))) short short8;
typedef __attribute__((ext_vector_type(4))) float f32x4;
typedef __attribute__((ext_vector_type(2))) float f32x2;
typedef __attribute__((ext_vector_type(4))) unsigned short us4;
}

__device__ __forceinline__ unsigned short f2bf(float f) {
  unsigned u = __builtin_bit_cast(unsigned, f);
  unsigned r = (u + 0x7FFFu + ((u >> 16) & 1u)) >> 16;
  return (unsigned short)r;
}
__device__ __forceinline__ float bf2f(unsigned short h) {
  unsigned u = (unsigned)h << 16;
  return __builtin_bit_cast(float, u);
}

// ||e||^2 (fp64+fp32), bf16 hi/lo codebook split; zeroes loss/ghist/dwf
// (so NO hipMemsetAsync dispatches are needed anywhere).
extern "C" __global__ void vq_se2(const float* __restrict__ emb,
                                  float* __restrict__ se32,
                                  double* __restrict__ se64,
                                  unsigned short* __restrict__ ehi,
                                  unsigned short* __restrict__ elo,
                                  float* __restrict__ loss_sum,
                                  int* __restrict__ ghist,
                                  float* __restrict__ dwf) {
  int j = blockIdx.x * blockDim.x + threadIdx.x;   // 0..511
  if (j == 0) loss_sum[0] = 0.f;
  if (j >= kNE) return;
  ghist[j] = 0;
  {
    f32x4 z = {0.f, 0.f, 0.f, 0.f};
    f32x4* dz = (f32x4*)(dwf + (size_t)j * kED);
    #pragma unroll
    for (int k = 0; k < 16; ++k) dz[k] = z;
  }
  const float4* e4 = (const float4*)(emb + (size_t)j * kED);
  double s = 0.0;
  for (int i = 0; i < 16; ++i) {
    float4 v = e4[i];
    s += (double)v.x * v.x + (double)v.y * v.y
       + (double)v.z * v.z + (double)v.w * v.w;
    us4 h, l;
    float f[4] = {v.x, v.y, v.z, v.w};
    unsigned short hh[4], ll[4];
    #pragma unroll
    for (int t = 0; t < 4; ++t) {
      hh[t] = f2bf(f[t]);
      ll[t] = f2bf(f[t] - bf2f(hh[t]));
    }
    h.x = hh[0]; h.y = hh[1]; h.z = hh[2]; h.w = hh[3];
    l.x = ll[0]; l.y = ll[1]; l.z = ll[2]; l.w = ll[3];
    *(us4*)&ehi[(size_t)j * kED + i * 4] = h;
    *(us4*)&elo[(size_t)j * kED + i * 4] = l;
  }
  se64[j] = s;
  se32[j] = (float)s;
}

// Fused: MFMA argmin + straight-through out + loss + token-major flat +
// one-hot encodings (268 MB NT stores overlap the compute phase).
extern "C" __global__ __launch_bounds__(kThreads) void vq_main(
    const float* __restrict__ x, const float* __restrict__ emb,
    const float* __restrict__ se32, const double* __restrict__ se64,
    const unsigned short* __restrict__ ehi, const unsigned short* __restrict__ elo,
    int* __restrict__ idx_out, float* __restrict__ out_q,
    float* __restrict__ enc, float* __restrict__ loss_sum,
    float* __restrict__ flat_ws, int write_flat) {
  __shared__ __attribute__((aligned(16))) unsigned short ahi[kTokPerBlk][72];
  __shared__ __attribute__((aligned(16))) unsigned short alo[kTokPerBlk][72];
  __shared__ __attribute__((aligned(16))) char bbuf[64 * 72 * 2 * 2]; // B hi+lo
  __shared__ float se_t[64];
  __shared__ float tok_best[kTokPerBlk];
  __shared__ float tok_sec[kTokPerBlk];
  __shared__ int   tok_idx[kTokPerBlk];
  __shared__ int   flag_list[kTokPerBlk];
  __shared__ int   flag_cnt;
  __shared__ float xbuf[kED];
  __shared__ float lred[4];
  unsigned short* bhi = (unsigned short*)bbuf;            // [64][72]
  unsigned short* blo = (unsigned short*)(bbuf + 9216);   // [64][72]
  double* redd = (double*)bbuf;            // rescue overlay
  int*    redj = (int*)(bbuf + 2048);
  float*  qt   = (float*)bbuf;             // [64][65] out-phase overlay

  const int tid = threadIdx.x;
  const int token_base = blockIdx.x * kTokPerBlk;
  const int batch = token_base / kHW;
  const int pos0  = token_base % kHW;     // tiles never cross batch

  if (tid == 0) flag_cnt = 0;

  // ---- stage x tile: transpose + bf16 hi/lo split in registers ----
  const float* xb = x + (size_t)batch * kED * kHW + pos0;
  {
    const int p  = tid & 63;
    const int d0 = tid >> 6;
    float xv[16];
    #pragma unroll
    for (int i = 0; i < 16; ++i)
      xv[i] = xb[(size_t)(d0 * 16 + i) * kHW + p];   // coalesced per i
    unsigned hp[8], lp[8];
    #pragma unroll
    for (int i = 0; i < 8; ++i) {
      unsigned short h0 = f2bf(xv[2*i]),  h1 = f2bf(xv[2*i+1]);
      unsigned short l0 = f2bf(xv[2*i]   - bf2f(h0));
      unsigned short l1 = f2bf(xv[2*i+1] - bf2f(h1));
      hp[i] = (unsigned)h0 | ((unsigned)h1 << 16);
      lp[i] = (unsigned)l0 | ((unsigned)l1 << 16);
    }
    uint4 h04 = {hp[0], hp[1], hp[2], hp[3]};
    uint4 h48 = {hp[4], hp[5], hp[6], hp[7]};
    uint4 l04 = {lp[0], lp[1], lp[2], lp[3]};
    uint4 l48 = {lp[4], lp[5], lp[6], lp[7]};
    *(uint4*)&ahi[p][d0 * 16]     = h04;
    *(uint4*)&ahi[p][d0 * 16 + 8] = h48;
    *(uint4*)&alo[p][d0 * 16]     = l04;
    *(uint4*)&alo[p][d0 * 16 + 8] = l48;
  }
  __syncthreads();

  // ---- per-wave A fragments ----
  const int lane = tid & 63;
  const int wv   = tid >> 6;
  const int qd   = lane >> 4;
  const int ml   = lane & 15;
  const int arow = wv * 16 + ml;
  const char* abase_h = (const char*)&ahi[0][0] + arow * 144 + qd * 16;
  const char* abase_l = (const char*)&alo[0][0] + arow * 144 + qd * 16;
  short8 a_h0 = *(const short8*)(abase_h);
  short8 a_h1 = *(const short8*)(abase_h + 64);
  short8 a_l0 = *(const short8*)(abase_l);
  short8 a_l1 = *(const short8*)(abase_l + 64);

  float bestv[4], secv[4];
  int   bestj[4];
  #pragma unroll
  for (int r = 0; r < 4; ++r) { bestv[r] = INFINITY; secv[r] = INFINITY; bestj[r] = 0; }

  // ---- 8 chunks of 64 codes: bf16x3 MFMA distances ----
  for (int c0 = 0; c0 < kNE; c0 += 64) {
    __syncthreads();
    {
      const char* srch = (const char*)ehi + (size_t)c0 * 128;
      const char* srcl = (const char*)elo + (size_t)c0 * 128;
      #pragma unroll
      for (int i = 0; i < 2; ++i) {
        int q = i * kThreads + tid;     // 0..511 (64 rows x 8 segs)
        int row = q >> 3, seg = q & 7;
        *(float4*)((char*)bhi + row * 144 + seg * 16) =
            *(const float4*)(srch + row * 128 + seg * 16);
        *(float4*)((char*)blo + row * 144 + seg * 16) =
            *(const float4*)(srcl + row * 128 + seg * 16);
      }
      if (tid < 64) se_t[tid] = se32[c0 + tid];
    }
    __syncthreads();

    for (int nt = 0; nt < 4; nt += 2) {
      const int cc0 = nt * 16 + ml;
      const int cc1 = cc0 + 16;
      const char* b0h = (const char*)bhi + cc0 * 144 + qd * 16;
      const char* b0l = (const char*)blo + cc0 * 144 + qd * 16;
      const char* b1h = (const char*)bhi + cc1 * 144 + qd * 16;
      const char* b1l = (const char*)blo + cc1 * 144 + qd * 16;
      short8 bh00 = *(const short8*)(b0h);
      short8 bh01 = *(const short8*)(b0h + 64);
      short8 bl00 = *(const short8*)(b0l);
      short8 bl01 = *(const short8*)(b0l + 64);
      short8 bh10 = *(const short8*)(b1h);
      short8 bh11 = *(const short8*)(b1h + 64);
      short8 bl10 = *(const short8*)(b1l);
      short8 bl11 = *(const short8*)(b1l + 64);

      f32x4 acc0 = {0.f, 0.f, 0.f, 0.f};
      f32x4 acc1 = {0.f, 0.f, 0.f, 0.f};
      acc0 = __builtin_amdgcn_mfma_f32_16x16x32_bf16(a_h0, bh00, acc0, 0, 0, 0);
      acc1 = __builtin_amdgcn_mfma_f32_16x16x32_bf16(a_h0, bh10, acc1, 0, 0, 0);
      acc0 = __builtin_amdgcn_mfma_f32_16x16x32_bf16(a_h1, bh01, acc0, 0, 0, 0);
      acc1 = __builtin_amdgcn_mfma_f32_16x16x32_bf16(a_h1, bh11, acc1, 0, 0, 0);
      acc0 = __builtin_amdgcn_mfma_f32_16x16x32_bf16(a_l0, bh00, acc0, 0, 0, 0);
      acc1 = __builtin_amdgcn_mfma_f32_16x16x32_bf16(a_l0, bh10, acc1, 0, 0, 0);
      acc0 = __builtin_amdgcn_mfma_f32_16x16x32_bf16(a_l1, bh01, acc0, 0, 0, 0);
      acc1 = __builtin_amdgcn_mfma_f32_16x16x32_bf16(a_l1, bh11, acc1, 0, 0, 0);
      acc0 = __builtin_amdgcn_mfma_f32_16x16x32_bf16(a_h0, bl00, acc0, 0, 0, 0);
      acc1 = __builtin_amdgcn_mfma_f32_16x16x32_bf16(a_h0, bl10, acc1, 0, 0, 0);
      acc0 = __builtin_amdgcn_mfma_f32_16x16x32_bf16(a_h1, bl01, acc0, 0, 0, 0);
      acc1 = __builtin_amdgcn_mfma_f32_16x16x32_bf16(a_h1, bl11, acc1, 0, 0, 0);

      const int j0 = c0 + cc0;
      const int j1 = c0 + cc1;
      const float s0 = se_t[cc0];
      const float s1 = se_t[cc1];
      #pragma unroll
      for (int r = 0; r < 4; ++r) {
        float v0 = s0 - 2.f * acc0[r];
        if (v0 < bestv[r]) { secv[r] = bestv[r]; bestv[r] = v0; bestj[r] = j0; }
        else secv[r] = fminf(secv[r], v0);
        float v1 = s1 - 2.f * acc1[r];
        if (v1 < bestv[r]) { secv[r] = bestv[r]; bestv[r] = v1; bestj[r] = j1; }
        else secv[r] = fminf(secv[r], v1);
      }
    }
  }

  // ---- cross-lane merge within each 16-lane quad group ----
  #pragma unroll
  for (int off = 1; off < 16; off <<= 1) {
    #pragma unroll
    for (int r = 0; r < 4; ++r) {
      float ov = __shfl_xor(bestv[r], off, 16);
      float os = __shfl_xor(secv[r], off, 16);
      int   oj = __shfl_xor(bestj[r], off, 16);
      bool take = (ov < bestv[r]) || (ov == bestv[r] && oj < bestj[r]);
      float loser = take ? bestv[r] : ov;
      bestv[r] = take ? ov : bestv[r];
      bestj[r] = take ? oj : bestj[r];
      secv[r]  = fminf(fminf(loser, os), secv[r]);
    }
  }
  if (ml == 0) {
    #pragma unroll
    for (int r = 0; r < 4; ++r) {
      int m = wv * 16 + qd * 4 + r;
      tok_best[m] = bestv[r];
      tok_sec[m]  = secv[r];
      tok_idx[m]  = bestj[r];
    }
  }
  __syncthreads();

  if (tid < kTokPerBlk) {
    if (tok_sec[tid] - tok_best[tid] < kMargin) {
      int p = atomicAdd(&flag_cnt, 1);
      flag_list[p] = tid;
    }
  }
  __syncthreads();   // all B reads done -> bbuf reusable

  // ---- exact fp64 rescan for flagged tokens (rare; overlays bbuf) ----
  const int nflag = flag_cnt;
  for (int fi = 0; fi < nflag; ++fi) {
    const int tr = flag_list[fi];
    if (tid < kED) xbuf[tid] = xb[(size_t)tid * kHW + tr];  // exact fp32 x
    __syncthreads();
    double db = 1e300; int dbj = 0;
    #pragma unroll 1
    for (int jj = 0; jj < 2; ++jj) {
      int j = tid * 2 + jj;
      const float* er = emb + (size_t)j * kED;
      double a0 = 0.0, a1 = 0.0, a2 = 0.0, a3 = 0.0;
      #pragma unroll
      for (int d = 0; d < kED; d += 4) {
        a0 = __builtin_fma((double)xbuf[d+0], (double)er[d+0], a0);
        a1 = __builtin_fma((double)xbuf[d+1], (double)er[d+1], a1);
        a2 = __builtin_fma((double)xbuf[d+2], (double)er[d+2], a2);
        a3 = __builtin_fma((double)xbuf[d+3], (double)er[d+3], a3);
      }
      double dist = se64[j] - 2.0 * ((a0 + a1) + (a2 + a3));
      if (dist < db || (dist == db && j < dbj)) { db = dist; dbj = j; }
    }
    redd[tid] = db; redj[tid] = dbj;
    __syncthreads();
    for (int s2 = kThreads / 2; s2 > 0; s2 >>= 1) {
      if (tid < s2) {
        double v = redd[tid + s2]; int j = redj[tid + s2];
        if (v < redd[tid] || (v == redd[tid] && j < redj[tid])) {
          redd[tid] = v; redj[tid] = j;
        }
      }
      __syncthreads();
    }
    if (tid == 0) tok_idx[tr] = redj[0];
    __syncthreads();
  }

  if (tid < kTokPerBlk) idx_out[token_base + tid] = tok_idx[tid];
  __syncthreads();   // rescue overlays done before qt staging

  // ---- gather assigned code rows (fp32) into qt (overlay bbuf) ----
  {
    int rr = tid >> 2;
    int c0 = (tid & 3) * 16;
    const float* er = emb + (size_t)tok_idx[rr] * kED;
    #pragma unroll
    for (int i = 0; i < 4; ++i) {
      float4 v = *(const float4*)(er + c0 + i * 4);
      qt[rr * 65 + c0 + i * 4 + 0] = v.x;
      qt[rr * 65 + c0 + i * 4 + 1] = v.y;
      qt[rr * 65 + c0 + i * 4 + 2] = v.z;
      qt[rr * 65 + c0 + i * 4 + 3] = v.w;
    }
  }
  __syncthreads();

  // ---- out (straight-through, NCHW, NT) + loss; inv = hi+lo ----
  float lacc = 0.f;
  {
    float* outb = out_q + (size_t)batch * kED * kHW + pos0;
    const int p  = tid & 63;
    const int c0 = tid >> 6;
    #pragma unroll
    for (int i = 0; i < 16; ++i) {
      int c = i * 4 + c0;
      float inv  = bf2f(ahi[p][c]) + bf2f(alo[p][c]);
      float qv   = qt[p * 65 + c];
      float diff = qv - inv;
      __builtin_nontemporal_store(inv + diff, &outb[(size_t)c * kHW + p]);
      lacc = __builtin_fmaf(diff, diff, lacc);
    }
  }

  // ---- token-major flat x for the dw stage ----
  if (write_flat) {
    const int r  = tid >> 2;
    const int d0 = (tid & 3) * 16;
    float* dst = flat_ws + (size_t)(token_base + r) * kED + d0;
    #pragma unroll
    for (int i = 0; i < 4; ++i) {
      f32x4 v;
      #pragma unroll
      for (int t = 0; t < 4; ++t)
        v[t] = bf2f(ahi[r][d0 + i*4 + t]) + bf2f(alo[r][d0 + i*4 + t]);
      *(f32x4*)(dst + i * 4) = v;
    }
  }

  // ---- one-hot encodings (fused; overlaps via NT write buffering) ----
  {
    f32x2* encb2 = (f32x2*)(enc + (size_t)token_base * kNE);
    #pragma unroll 4
    for (int i = 0; i < 64; ++i) {
      int q = i * kThreads + tid;   // float2 idx, 0..16383
      int row = q >> 8;
      int c2  = (q & 255) * 2;
      int bi = tok_idx[row];
      f32x2 v;
      v.x = (bi == c2)     ? 1.f : 0.f;
      v.y = (bi == c2 + 1) ? 1.f : 0.f;
      __builtin_nontemporal_store(v, &encb2[q]);
    }
  }

  #pragma unroll
  for (int off = 32; off > 0; off >>= 1) lacc += __shfl_down(lacc, off, 64);
  if ((tid & 63) == 0) lred[tid >> 6] = lacc;
  __syncthreads();
  if (tid == 0)
    atomicAdd(loss_sum, (lred[0] + lred[1]) + (lred[2] + lred[3]));
}

// ---- dw chain: hist64 -> scan1 -> scatter2 -> dw_chunk ----
extern "C" __global__ __launch_bounds__(kThreads) void vq_hist64(
    const int* __restrict__ idx, int* __restrict__ ghist) {
  __shared__ int h[kNE];
  const int tid = threadIdx.x, b = blockIdx.x;
  h[tid] = 0; h[tid + 256] = 0;
  __syncthreads();
  #pragma unroll
  for (int it = 0; it < 8; ++it)
    atomicAdd(&h[idx[b * 2048 + it * 256 + tid]], 1);
  __syncthreads();
  if (h[tid]) atomicAdd(&ghist[tid], h[tid]);
  if (h[tid + 256]) atomicAdd(&ghist[tid + 256], h[tid + 256]);
}

// 1 block, 512 threads: exclusive scan of ghist -> cur; ghist -> cnt (float,
// in place).
extern "C" __global__ __launch_bounds__(512) void vq_scan1(
    int* __restrict__ ghist_cnt, int* __restrict__ cur) {
  __shared__ int sh[kNE];
  const int c = threadIdx.x;
  int v = ghist_cnt[c];
  sh[c] = v;
  __syncthreads();
  #pragma unroll 1
  for (int off = 1; off < kNE; off <<= 1) {
    int t = (c >= off) ? sh[c - off] : 0;
    __syncthreads();
    sh[c] += t;
    __syncthreads();
  }
  cur[c] = sh[c] - v;
  ((float*)ghist_cnt)[c] = (float)v;
}

// 64 blocks: local hist -> global range reservation -> LDS-rank placement.
// Within-cluster order is nondeterministic (only perturbs fp32 dw sum order).
extern "C" __global__ __launch_bounds__(kThreads) void vq_scatter2(
    const int* __restrict__ idx, int* __restrict__ cur,
    int* __restrict__ sorted) {
  __shared__ int h[kNE];
  __shared__ int base[kNE];
  const int tid = threadIdx.x, b = blockIdx.x;
  h[tid] = 0; h[tid + 256] = 0;
  __syncthreads();
  #pragma unroll
  for (int it = 0; it < 8; ++it)
    atomicAdd(&h[idx[b * 2048 + it * 256 + tid]], 1);
  __syncthreads();
  if (h[tid]) base[tid] = atomicAdd(&cur[tid], h[tid]);
  if (h[tid + 256]) base[tid + 256] = atomicAdd(&cur[tid + 256], h[tid + 256]);
  __syncthreads();
  h[tid] = 0; h[tid + 256] = 0;
  __syncthreads();
  #pragma unroll
  for (int it = 0; it < 8; ++it) {
    int i = b * 2048 + it * 256 + tid;
    int c = idx[i];
    int r = atomicAdd(&h[c], 1);
    sorted[base[c] + r] = (c << 17) | i;
  }
}

// Load-balanced dw: 1024 blocks x 128 sorted tokens, register run-accumulation
// over the non-decreasing code sequence, atomic flush on code change.
extern "C" __global__ __launch_bounds__(kThreads) void vq_dw_chunk(
    const float* __restrict__ flat, const int* __restrict__ sorted,
    float* __restrict__ dwf) {
  __shared__ int spk[128];
  const int tid = threadIdx.x;
  const int base = blockIdx.x * 128;
  if (tid < 128) spk[tid] = sorted[base + tid];
  __syncthreads();
  const int tt = tid >> 6, d = tid & 63;
  int cur_c = -1;
  float acc = 0.f;
  #pragma unroll 1
  for (int bi = 0; bi < 8; ++bi) {
    int p = tt * 32 + bi * 4;
    int k0 = spk[p], k1 = spk[p + 1], k2 = spk[p + 2], k3 = spk[p + 3];
    float v0 = flat[(size_t)(k0 & 131071) * kED + d];
    float v1 = flat[(size_t)(k1 & 131071) * kED + d];
    float v2 = flat[(size_t)(k2 & 131071) * kED + d];
    float v3 = flat[(size_t)(k3 & 131071) * kED + d];
    int c0 = k0 >> 17, c1 = k1 >> 17, c2 = k2 >> 17, c3 = k3 >> 17;
    if (c0 != cur_c) {
      if (cur_c >= 0) atomicAdd(&dwf[cur_c * kED + d], acc);
      acc = 0.f; cur_c = c0;
    }
    acc += v0;
    if (c1 != cur_c) { atomicAdd(&dwf[cur_c * kED + d], acc); acc = 0.f; cur_c = c1; }
    acc += v1;
    if (c2 != cur_c) { atomicAdd(&dwf[cur_c * kED + d], acc); acc = 0.f; cur_c = c2; }
    acc += v2;
    if (c3 != cur_c) { atomicAdd(&dwf[cur_c * kED + d], acc); acc = 0.f; cur_c = c3; }
    acc += v3;
  }
  atomicAdd(&dwf[cur_c * kED + d], acc);
}

// ---- fallback path (small ws): per-block LDS partials + dense reduce ----
extern "C" __global__ __launch_bounds__(kThreads) void vq_dw_part(
    const float* __restrict__ x, const int* __restrict__ idx,
    float* __restrict__ part, int G) {
  __shared__ float dwacc[kNE * kED];
  __shared__ int   hist[kNE];
  __shared__ float flat[kTokPerBlk][65];
  __shared__ int   idxs[kTokPerBlk];
  const int tid = threadIdx.x;
  #pragma unroll
  for (int i = 0; i < kNE * kED / kThreads; ++i) dwacc[i * kThreads + tid] = 0.f;
  for (int i = tid; i < kNE; i += kThreads) hist[i] = 0;
  __syncthreads();
  for (int tile = blockIdx.x; tile < kNTiles; tile += G) {
    const int token_base = tile * kTokPerBlk;
    const int batch = token_base / kHW;
    const int pos0  = token_base % kHW;
    const float* xb = x + (size_t)batch * kED * kHW + pos0;
    {
      const int p  = tid & 63;
      const int d0 = tid >> 6;
      #pragma unroll
      for (int i = 0; i < 16; ++i) {
        int d = i * 4 + d0;
        flat[p][d] = xb[(size_t)d * kHW + p];
      }
    }
    if (tid < kTokPerBlk) idxs[tid] = idx[token_base + tid];
    __syncthreads();
    {
      const int w = tid >> 6;
      const int d = tid & 63;
      #pragma unroll
      for (int i = 0; i < 16; ++i) {
        int rr = w + i * 4;
        atomicAdd(&dwacc[idxs[rr] * kED + d], flat[rr][d]);
      }
    }
    if (tid < kTokPerBlk) atomicAdd(&hist[idxs[tid]], 1);
    __syncthreads();
  }
  float* dst = part + (size_t)blockIdx.x * kPartStride;
  #pragma unroll
  for (int i = 0; i < kNE * kED / kThreads / 4; ++i) {
    int q = i * kThreads + tid;
    *(float4*)&dst[q * 4] = *(float4*)&dwacc[q * 4];
  }
  #pragma unroll
  for (int i = 0; i < kNE / kThreads; ++i) {
    int q = i * kThreads + tid;
    dst[kNE * kED + q] = (float)hist[q];
  }
}

extern "C" __global__ void vq_red(const float* __restrict__ part,
                                  float* __restrict__ dwf,
                                  float* __restrict__ cnt, int G) {
  int i = blockIdx.x * blockDim.x + threadIdx.x;
  if (i >= kPartStride) return;
  float s0 = 0.f, s1 = 0.f, s2 = 0.f, s3 = 0.f;
  int p = 0;
  for (; p + 3 < G; p += 4) {
    s0 += part[(size_t)(p + 0) * kPartStride + i];
    s1 += part[(size_t)(p + 1) * kPartStride + i];
    s2 += part[(size_t)(p + 2) * kPartStride + i];
    s3 += part[(size_t)(p + 3) * kPartStride + i];
  }
  for (; p < G; ++p) s0 += part[(size_t)p * kPartStride + i];
  float s = (s0 + s1) + (s2 + s3);
  if (i < kNE * kED) dwf[i] = s;
  else cnt[i - kNE * kED] = s;
}

extern "C" __global__ __launch_bounds__(kThreads) void vq_dw_atomic(
    const float* __restrict__ x, const int* __restrict__ idx,
    float* __restrict__ dwf, float* __restrict__ cnt) {
  __shared__ float flat[kTokPerBlk][65];
  __shared__ int   idxs[kTokPerBlk];
  const int tid = threadIdx.x;
  const int token_base = blockIdx.x * kTokPerBlk;
  const int batch = token_base / kHW;
  const int pos0  = token_base % kHW;
  const float* xb = x + (size_t)batch * kED * kHW + pos0;
  {
    const int p  = tid & 63;
    const int d0 = tid >> 6;
    #pragma unroll
    for (int i = 0; i < 16; ++i) {
      int d = i * 4 + d0;
      flat[p][d] = xb[(size_t)d * kHW + p];
    }
  }
  if (tid < kTokPerBlk) idxs[tid] = idx[token_base + tid];
  __syncthreads();
  {
    int rr = tid >> 2;
    int c0 = (tid & 3) * 16;
    float* dwr = dwf + (size_t)idxs[rr] * kED;
    #pragma unroll
    for (int i = 0; i < 16; ++i) atomicAdd(&dwr[c0 + i], flat[rr][c0 + i]);
  }
  if (tid < kTokPerBlk) atomicAdd(&cnt[idxs[tid]], 1.0f);
}

// cluster Laplace smoothing, perplexity, loss
extern "C" __global__ void vq_fin_a(const float* __restrict__ ema_cs,
                                    const float* __restrict__ counts,
                                    const float* __restrict__ loss_sum,
                                    float* __restrict__ out) {
  __shared__ float red[kNE];
  const int j = threadIdx.x;
  float craw = ema_cs[j] * 0.99f + 0.01f * counts[j];
  red[j] = craw;
  __syncthreads();
  for (int s = kNE / 2; s > 0; s >>= 1) {
    if (j < s) red[j] += red[j + s];
    __syncthreads();
  }
  float k = red[0];
  __syncthreads();
  float clu = (craw + 1e-5f) / (k + kNE * 1e-5f) * k;
  out[O_CLUSTER + j] = clu;
  float avg = counts[j] * (1.0f / 131072.0f);
  float term = avg * logf(avg + 1e-10f);
  red[j] = term;
  __syncthreads();
  for (int s = kNE / 2; s > 0; s >>= 1) {
    if (j < s) red[j] += red[j + s];
    __syncthreads();
  }
  if (j == 0) {
    out[O_PERP] = expf(-red[0]);
    out[O_LOSS] = 0.25f * loss_sum[0] * (1.0f / 8388608.0f);
  }
}

// new_ema_w + new_embedding (blocks 0..63) and enc fixup for tokens 0..255
// whose one-hot rows were used as `sorted` scratch (blocks 64..127).
extern "C" __global__ __launch_bounds__(kThreads) void vq_fin_b(
    const float* __restrict__ ema_w, const float* __restrict__ dw,
    const float* __restrict__ out_cluster, float* __restrict__ out,
    const int* __restrict__ idx) {
  const int b = blockIdx.x, tid = threadIdx.x;
  if (b < 64) {
    int i = b * 512 + tid;
    #pragma unroll
    for (int k = 0; k < 2; ++k, i += 256) {
      int j = i >> 6;
      float nw = ema_w[i] * 0.99f + 0.01f * dw[i];
      out[O_NEWEMAW + i] = nw;
      out[O_NEWEMB + i] = nw / out_cluster[j];
    }
  } else {
    int t  = (b - 64) * 4 + (tid >> 6);   // token 0..255
    int bi = idx[t];
    int c0 = (tid & 63) * 8;
    float* er = out + O_ENC + (size_t)t * kNE + c0;
    #pragma unroll
    for (int k = 0; k < 4; ++k) {
      f32x2 v;
      v.x = (c0 + 2 * k     == bi) ? 1.f : 0.f;
      v.y = (c0 + 2 * k + 1 == bi) ? 1.f : 0.f;
      *(f32x2*)(er + 2 * k) = v;
    }
  }
}

extern "C" void kernel_launch(void* const* d_in, const int* in_sizes, int n_in,
                              void* d_out, int out_size, void* d_ws, size_t ws_size,
                              hipStream_t stream) {
  const float* x      = (const float*)d_in[0];
  const float* emb    = (const float*)d_in[1];
  const float* ema_w  = (const float*)d_in[2];
  const float* ema_cs = (const float*)d_in[3];
  float* out = (float*)d_out;
  float* ws  = (float*)d_ws;

  int*    idxb     = (int*)d_ws;
  float*  loss_sum = ws + F_LOSS;
  float*  se32     = ws + F_SE32;
  double* se64     = (double*)(ws + F_SE64);
  unsigned short* ehi = (unsigned short*)(ws + F_EHI);
  unsigned short* elo = (unsigned short*)(ws + F_ELO);
  int*    ghist    = (int*)(ws + F_CNT);   // ints, becomes float cnt in scan1
  float*  cnt      = ws + F_CNT;
  float*  dwf      = ws + F_DW;
  float*  aux      = ws + F_AUX;           // flat (token-major x) OR partials
  int*    cur      = (int*)(ws + F_SE32);  // reuse se32 slot after vq_main
  int*    sorted   = (int*)(out + O_ENC);  // enc scratch; fixed up by vq_fin_b

  const size_t need_flat = (F_AUX + (size_t)kNTok * kED) * 4;
  const bool flat_ok = ws_size >= need_flat;
  int G = 0;
  if (!flat_ok) {
    long avail = (long)(ws_size / 4) - (long)F_AUX;
    G = avail > 0 ? (int)(avail / kPartStride) : 0;
    if (G > 256) G = 256;
  }
  const bool part_ok = (G >= 8);

  // se2 zeroes loss/ghist(cnt)/dwf -> no memset dispatches needed
  hipLaunchKernelGGL(vq_se2, dim3(2), dim3(256), 0, stream,
                     emb, se32, se64, ehi, elo, loss_sum, ghist, dwf);
  hipLaunchKernelGGL(vq_main, dim3(kNTiles), dim3(kThreads), 0, stream,
                     x, emb, se32, se64, ehi, elo, idxb, out + O_OUT,
                     out + O_ENC, loss_sum, aux, flat_ok ? 1 : 0);
  if (flat_ok) {
    hipLaunchKernelGGL(vq_hist64, dim3(64), dim3(kThreads), 0, stream,
                       idxb, ghist);
    hipLaunchKernelGGL(vq_scan1, dim3(1), dim3(512), 0, stream,
                       ghist, cur);
    hipLaunchKernelGGL(vq_scatter2, dim3(64), dim3(kThreads), 0, stream,
                       idxb, cur, sorted);
    hipLaunchKernelGGL(vq_dw_chunk, dim3(kNTok / 128), dim3(kThreads), 0, stream,
                       aux, sorted, dwf);
  } else if (part_ok) {
    hipLaunchKernelGGL(vq_dw_part, dim3(G), dim3(kThreads), 0, stream,
                       x, idxb, aux, G);
    hipLaunchKernelGGL(vq_red, dim3((kPartStride + 255) / 256), dim3(256), 0,
                       stream, aux, dwf, cnt, G);
  } else {
    hipLaunchKernelGGL(vq_dw_atomic, dim3(kNTiles), dim3(kThreads), 0, stream,
                       x, idxb, dwf, cnt);
  }
  hipLaunchKernelGGL(vq_fin_a, dim3(1), dim3(kNE), 0, stream,
                     ema_cs, cnt, loss_sum, out);
  // fin_b also repairs the enc rows used as `sorted` scratch (after dw_chunk)
  hipLaunchKernelGGL(vq_fin_b, dim3(128), dim3(kThreads), 0, stream,
                     ema_w, dwf, out + O_CLUSTER, out, idxb);
}